// Round 5
// baseline (276.309 us; speedup 1.0000x reference)
//
#include <hip/hip_runtime.h>
#include <hip/hip_cooperative_groups.h>

namespace cg = cooperative_groups;

#define N_NODES 100000
#define IN_CH 32
#define EDGE_CH 16
#define OUT_CH 32
#define D_CAT 80
#define D_MID 56

// fine buckets: 64 nodes each
#define BKT_SHIFT 6
#define BKT_NODES 64
#define NB 1563            // ceil(100000/64)
#define NB_ALL 1568        // padded
#define CAP 1024           // fine bucket capacity (mean 640, sd 25)

// fallback-path constants (super buckets)
#define NSUP 196
#define CAP_SUP 5632
#define K1_EDGES 2048
#define K1_EPT 4
#define K2_SPLIT 4
#define K2_SLICE 1408
#define K2_SITERS 3

#define COOP_GRID 512      // 2 blocks/CU x 256 CU (LDS 76.8KB -> exactly 2/CU)

#define EPB 256            // edges per chunk (512 threads: slot=t>>1, q=t&1)
#define NT_E 16

// fragment-major sizes (shorts)
#define W1F_SH 4096        // 2ks * 4nt * 64lane * 8   (K=64: src32 + ea16 + pad16)
#define W2F_SH 2048        // 2ks * 2nt * 64lane * 8
#define W1D_SH 2048        // 1ks * 4nt * 64lane * 8   (dst rows 32..63 of W1)
#define WIMG_SH (W1F_SH + W2F_SH + W1D_SH)   // 8192 shorts = 16384 B
#define FEATF_SH (NT_E * 2 * 64 * 8)         // 16384 shorts = 32768 B (aliased by sHF + phase-A hist)

#define HSTRIDE 68
#define AGG_LD 33
#define ENC_NEGINF 0x007FFFFFu

typedef short short8 __attribute__((ext_vector_type(8)));
typedef float f32x4 __attribute__((ext_vector_type(4)));
typedef int i32x2 __attribute__((ext_vector_type(2)));

// ---- ws layout (bytes) ----
#define WS_IMG    0
#define WS_B1     16384
#define WS_B2     16640
#define WS_SUPCNT 16768
#define WS_GCNT   17664                    // 1568*4 = 6272
#define WS_Z0     16768
#define WS_ZSZ    (17664 + 6272 - 16768)   // 7168
#define WS_SUPREC 24576                    // fallback tier A
#define WS_REC    8855552                  // fallback tier A rec
#define WS_XB_A   21700608
#define XB_BYTES  6400000                  // 100000*32*2
#define WS_NEED_A ((size_t)WS_XB_A)
#define WS_NEED_AX ((size_t)WS_XB_A + XB_BYTES)
// fused/tier-B layout: rec directly at 24576
#define WS_XB_B   12869632                 // 24576 + NB_ALL*CAP*8
#define WS_NEED_B ((size_t)WS_XB_B)
#define WS_NEED_BX ((size_t)WS_XB_B + XB_BYTES)

__device__ __forceinline__ unsigned fenc(float f) {
    unsigned u = __float_as_uint(f);
    return (u & 0x80000000u) ? ~u : (u | 0x80000000u);
}
__device__ __forceinline__ float fdec(unsigned u) {
    u = (u & 0x80000000u) ? (u ^ 0x80000000u) : ~u;
    return __uint_as_float(u);
}
__device__ __forceinline__ float bfr(float f) {          // RNE to bf16 grid, as f32
    unsigned u = __float_as_uint(f);
    u = (u + 0x7FFFu + ((u >> 16) & 1u)) & 0xFFFF0000u;
    return __uint_as_float(u);
}
__device__ __forceinline__ unsigned short bf16b(float f) {  // RNE to bf16 bits
    unsigned u = __float_as_uint(f);
    return (unsigned short)((u + 0x7FFFu + ((u >> 16) & 1u)) >> 16);
}
__device__ __forceinline__ short8 cvt8(float4 a, float4 b) {
    return short8{ (short)bf16b(a.x), (short)bf16b(a.y), (short)bf16b(a.z), (short)bf16b(a.w),
                   (short)bf16b(b.x), (short)bf16b(b.y), (short)bf16b(b.z), (short)bf16b(b.w) };
}

__device__ __forceinline__ void convert_x_bf16(const float* __restrict__ x,
                                               unsigned short* __restrict__ xb,
                                               int gtid, int gstride) {
    const int tot = N_NODES * IN_CH / 8;   // 400000
    for (int i = gtid; i < tot; i += gstride) {
        float4 a = ((const float4*)x)[2 * i];
        float4 b = ((const float4*)x)[2 * i + 1];
        *(short8*)&xb[i * 8] = cvt8(a, b);
    }
}

// fragment-major weight images (see round-2 notes): W1F (K=64 src+ea), W2F, W1dF
__device__ void build_weight_image(const float* __restrict__ W1, const float* __restrict__ b1,
                                   const float* __restrict__ W2, const float* __restrict__ b2,
                                   unsigned short* __restrict__ wsImg,
                                   float* __restrict__ wsb1, float* __restrict__ wsb2,
                                   int t, int nthr) {
    for (int s = t; s < W1F_SH; s += nthr) {
        int j = s & 7, l = (s >> 3) & 63, fi = s >> 9;
        int nt = fi & 3, ks = fi >> 2;
        int n = nt * 16 + (l & 15), kl = ks * 32 + (l >> 4) * 8 + j;
        unsigned short v = 0;
        if (n < D_MID) {
            if (kl < 32) v = bf16b(W1[kl * D_MID + n]);
            else if (kl < 48) v = bf16b(W1[(64 + kl - 32) * D_MID + n]);
        }
        wsImg[s] = v;
    }
    for (int s = t; s < W2F_SH; s += nthr) {
        int j = s & 7, l = (s >> 3) & 63, fi = s >> 9;
        int nt = fi & 1, ks = fi >> 1;
        int n = nt * 16 + (l & 15), kl = ks * 32 + (l >> 4) * 8 + j;
        wsImg[W1F_SH + s] = (kl < D_MID) ? bf16b(W2[kl * OUT_CH + n]) : (unsigned short)0;
    }
    for (int s = t; s < W1D_SH; s += nthr) {
        int j = s & 7, l = (s >> 3) & 63, fi = s >> 9;
        int nt = fi & 3;
        int n = nt * 16 + (l & 15), kl = (l >> 4) * 8 + j;
        wsImg[W1F_SH + W2F_SH + s] = (n < D_MID) ? bf16b(W1[(32 + kl) * D_MID + n]) : (unsigned short)0;
    }
    if (t < 64) wsb1[t] = (t < D_MID) ? bfr(b1[t]) : 0.f;
    else if (t < 96) wsb2[t - 64] = bfr(b2[t - 64]);
}

// ================= fused cooperative kernel =================
// Phase A (all 512 blocks): single-level binning into rec (register-held edges, LDS
// histogram over all NB fine buckets aliased onto sFeatF, global base reservation,
// direct writes) + x->bf16 conversion + weight image (block 0). grid.sync().
// Phase B: each block loops over buckets b = blk, blk+512, ... running the proven
// bucket_mlp body (weights loaded into LDS once per block).
template<int XB>
__global__ __launch_bounds__(512, 4) void fused_all(
    const float* __restrict__ x, unsigned short* __restrict__ xb,
    const float* __restrict__ ea, const int* __restrict__ ei, int nE,
    int* __restrict__ gCnt, int2* __restrict__ rec,
    const float* __restrict__ W1, const float* __restrict__ b1,
    const float* __restrict__ W2, const float* __restrict__ b2,
    unsigned short* __restrict__ wsImg, float* __restrict__ wsb1, float* __restrict__ wsb2,
    float* __restrict__ out)
{
    __shared__ unsigned short sFeatF[FEATF_SH];   // 32768 B; phase A hist + phase B feat/HF
    __shared__ unsigned short sWgt[WIMG_SH];      // 16384 B
    __shared__ float sHdst[BKT_NODES * HSTRIDE];  // 17408 B
    __shared__ unsigned aggL[BKT_NODES * AGG_LD]; //  8448 B
    __shared__ float sb1f[64];
    __shared__ float sb2f[32];
    __shared__ int sdl[EPB];                      //  1024 B

    const int t = threadIdx.x;
    const int blk = blockIdx.x, nblk = gridDim.x;

    // ---------------- phase A ----------------
    {
        int* const lh = (int*)sFeatF;              // NB ints
        int* const lbase = ((int*)sFeatF) + NB;    // NB ints (12.5 KB total, fits)
        if (blk == 0) build_weight_image(W1, b1, W2, b2, wsImg, wsb1, wsb2, t, 512);
        if constexpr (XB) convert_x_bf16(x, xb, blk * 512 + t, nblk * 512);
        for (int i = t; i < NB; i += 512) lh[i] = 0;
        __syncthreads();

        const int per = (nE + nblk - 1) / nblk;    // 1954 at grid=512 -> 4 regs/thread
        const int lo = blk * per, hi = min(lo + per, nE);
        int rdst[4], rsrc[4];
#pragma unroll
        for (int k = 0; k < 4; ++k) {
            int e = lo + k * 512 + t;
            bool v = e < hi;
            rdst[k] = v ? __builtin_nontemporal_load(ei + nE + e) : -1;
            rsrc[k] = v ? __builtin_nontemporal_load(ei + e) : 0;
            if ((unsigned)rdst[k] >= N_NODES) rdst[k] = -1;
            if ((unsigned)rsrc[k] >= N_NODES) rsrc[k] = 0;
            if (rdst[k] >= 0) atomicAdd(&lh[rdst[k] >> BKT_SHIFT], 1);
        }
        __syncthreads();
        for (int i = t; i < NB; i += 512) {
            int c = lh[i];
            lbase[i] = c ? atomicAdd(&gCnt[i], c) : 0;
            lh[i] = 0;
        }
        __syncthreads();
#pragma unroll
        for (int k = 0; k < 4; ++k) {
            if (rdst[k] >= 0) {
                int b = rdst[k] >> BKT_SHIFT;
                int p = lbase[b] + atomicAdd(&lh[b], 1);
                if (p < CAP) {
                    int e = lo + k * 512 + t;
                    rec[(size_t)b * CAP + p] = make_int2(rsrc[k], ((rdst[k] & 63) << 20) | e);
                }
            }
        }
    }

    cg::this_grid().sync();   // binning + xb + weight image visible device-wide

    // ---------------- phase B ----------------
    unsigned short* const sW1F = sWgt;
    unsigned short* const sW2F = sWgt + W1F_SH;
    unsigned short* const sW1D = sWgt + W1F_SH + W2F_SH;
    unsigned short* const sHF  = sFeatF;

    for (int i = t; i < WIMG_SH / 8; i += 512)
        *(short8*)&sWgt[i * 8] = *(const short8*)(wsImg + i * 8);
    if (t < 64) sb1f[t] = wsb1[t];
    else if (t < 96) sb2f[t - 64] = wsb2[t - 64];

    const int wave = t >> 6;
    const int l15  = t & 15;
    const int quad = (t & 63) >> 4;
    const int lane = t & 63;
    const int slot = t >> 1, q = t & 1;
    const int sl15 = slot & 15, set = slot >> 4;

    for (int b = blk; b < NB; b += nblk) {
        const int nodeBase = b << BKT_SHIFT;
        const int base = b * CAP;
        const int cnt  = min(gCnt[b], CAP);

        __syncthreads();   // prev bucket's finalize/ep reads done; sWgt visible (1st iter)
        for (int i = t; i < BKT_NODES * AGG_LD; i += 512) aggL[i] = ENC_NEGINF;

        short8 rv16[4];
        int rdl;
        auto loadRec = [&](int idx) -> i32x2 {
            return (idx < cnt) ? *(const i32x2*)(rec + base + idx) : (i32x2){0, 0};
        };
        auto gather = [&](i32x2 r2, bool ok) {
            rdl = ok ? ((r2.y >> 20) & 63) : -1;
            short8 z = {0, 0, 0, 0, 0, 0, 0, 0};
            if (q == 0) {
                if constexpr (XB) {
                    const short8* xs8 = (const short8*)(xb + (size_t)r2.x * IN_CH);
#pragma unroll
                    for (int k = 0; k < 4; ++k) rv16[k] = ok ? xs8[k] : z;
                } else {
                    const float* xs = x + (size_t)r2.x * IN_CH;
#pragma unroll
                    for (int k = 0; k < 4; ++k)
                        rv16[k] = ok ? cvt8(((const float4*)xs)[2 * k], ((const float4*)xs)[2 * k + 1]) : z;
                }
            } else {
                const float* ep = ea + (size_t)(r2.y & 0xFFFFF) * EDGE_CH;
#pragma unroll
                for (int k = 0; k < 2; ++k)
                    rv16[k] = ok ? cvt8(((const float4*)ep)[2 * k], ((const float4*)ep)[2 * k + 1]) : z;
                rv16[2] = z; rv16[3] = z;
            }
        };
        auto storeChunk = [&]() {
            if (q == 0) sdl[slot] = rdl;
#pragma unroll
            for (int k = 0; k < 4; ++k) {
                int cj = q * 4 + k;
                int a16 = (set * 2 + (cj >> 2)) * 64 + (cj & 3) * 16 + sl15;
                *(short8*)&sFeatF[a16 * 8] = rv16[k];
            }
        };

        i32x2 recC = loadRec(slot);
        i32x2 recN = loadRec(EPB + slot);
        gather(recC, slot < cnt);

        // per-node dst pre-GEMM: sHdst[node][c] = (W1d . x_dst)[c] + b1[c]
        {
            const int ntile = wave & 3, mh = wave >> 2;
            int node = nodeBase + ntile * 16 + l15;
            short8 bfr8 = {0, 0, 0, 0, 0, 0, 0, 0};
            if (node < N_NODES) {
                if constexpr (XB) {
                    bfr8 = *(const short8*)(xb + (size_t)node * IN_CH + quad * 8);
                } else {
                    const float* xp = x + (size_t)node * IN_CH + quad * 8;
                    bfr8 = cvt8(((const float4*)xp)[0], ((const float4*)xp)[1]);
                }
            }
            f32x4 accd[2] = {(f32x4){0.f, 0.f, 0.f, 0.f}, (f32x4){0.f, 0.f, 0.f, 0.f}};
#pragma unroll
            for (int i = 0; i < 2; ++i) {
                int nt = mh * 2 + i;
                short8 af = *(const short8*)&sW1D[(nt * 64 + lane) * 8];
                accd[i] = __builtin_amdgcn_mfma_f32_16x16x32_bf16(af, bfr8, accd[i], 0, 0, 0);
            }
#pragma unroll
            for (int i = 0; i < 2; ++i) {
                int nt = mh * 2 + i, c0 = nt * 16 + quad * 4;
                float4 vv;
#pragma unroll
                for (int j = 0; j < 4; ++j) {
                    int c = c0 + j;
                    ((float*)&vv)[j] = (c < D_MID) ? accd[i][j] + sb1f[c] : 0.f;
                }
                *(float4*)&sHdst[(ntile * 16 + l15) * HSTRIDE + c0] = vv;
            }
        }
        // sHdst/aggL writes ordered before first reads via the in-loop barriers below

        for (int c0e = 0; c0e < cnt; c0e += EPB) {
            storeChunk();
            __syncthreads();
            gather(recN, (c0e + EPB + slot) < cnt);
            recN = loadRec(c0e + 2 * EPB + slot);

            // GEMM1: K=64; each wave owns edge tiles {wave, wave+8}
            f32x4 acc[2][4];
#pragma unroll
            for (int ei2 = 0; ei2 < 2; ++ei2)
#pragma unroll
                for (int nt = 0; nt < 4; ++nt) acc[ei2][nt] = (f32x4){0.f, 0.f, 0.f, 0.f};
#pragma unroll
            for (int ks = 0; ks < 2; ++ks) {
                short8 bf0 = *(const short8*)&sFeatF[((wave * 2 + ks) * 64 + lane) * 8];
                short8 bf1 = *(const short8*)&sFeatF[(((wave + 8) * 2 + ks) * 64 + lane) * 8];
#pragma unroll
                for (int nt = 0; nt < 4; ++nt) {
                    short8 af = *(const short8*)&sW1F[((ks * 4 + nt) * 64 + lane) * 8];
                    acc[0][nt] = __builtin_amdgcn_mfma_f32_16x16x32_bf16(af, bf0, acc[0][nt], 0, 0, 0);
                    acc[1][nt] = __builtin_amdgcn_mfma_f32_16x16x32_bf16(af, bf1, acc[1][nt], 0, 0, 0);
                }
            }
            __syncthreads();

            // epilogue1: add sHdst[dl] (has b1), LeakyReLU, -> fragment-major sHF
#pragma unroll
            for (int ei2 = 0; ei2 < 2; ++ei2) {
                int et = wave + ei2 * 8;
                int dl = sdl[et * 16 + l15];
                const float* hrow = &sHdst[((dl >= 0) ? dl : 0) * HSTRIDE];
#pragma unroll
                for (int nt = 0; nt < 4; ++nt) {
                    int c0 = nt * 16 + quad * 4;
                    float4 hd = *(const float4*)&hrow[c0];
                    int ks2 = nt >> 1;
                    int quad2 = (nt * 2 + (quad >> 1)) & 3;
                    int off = (quad & 1) * 4;
                    ushort4 p;
#pragma unroll
                    for (int j = 0; j < 4; ++j) {
                        float v = acc[ei2][nt][j] + ((const float*)&hd)[j];
                        v = (v > 0.f) ? v : 0.01f * v;
                        ((unsigned short*)&p)[j] = (c0 + j < D_MID) ? bf16b(v) : (unsigned short)0;
                    }
                    *(ushort4*)&sHF[((et * 2 + ks2) * 64 + quad2 * 16 + l15) * 8 + off] = p;
                }
            }
            __syncthreads();

            // GEMM2
            f32x4 acc2[2][2];
#pragma unroll
            for (int ei2 = 0; ei2 < 2; ++ei2)
#pragma unroll
                for (int nt = 0; nt < 2; ++nt) acc2[ei2][nt] = (f32x4){0.f, 0.f, 0.f, 0.f};
#pragma unroll
            for (int ks = 0; ks < 2; ++ks) {
                short8 bf0 = *(const short8*)&sHF[((wave * 2 + ks) * 64 + lane) * 8];
                short8 bf1 = *(const short8*)&sHF[(((wave + 8) * 2 + ks) * 64 + lane) * 8];
#pragma unroll
                for (int nt = 0; nt < 2; ++nt) {
                    short8 af = *(const short8*)&sW2F[((ks * 2 + nt) * 64 + lane) * 8];
                    acc2[0][nt] = __builtin_amdgcn_mfma_f32_16x16x32_bf16(af, bf0, acc2[0][nt], 0, 0, 0);
                    acc2[1][nt] = __builtin_amdgcn_mfma_f32_16x16x32_bf16(af, bf1, acc2[1][nt], 0, 0, 0);
                }
            }

            // epilogue2: LDS scatter-max
#pragma unroll
            for (int ei2 = 0; ei2 < 2; ++ei2) {
                int et = wave + ei2 * 8;
                int dl = sdl[et * 16 + l15];
                if (dl >= 0) {
                    unsigned* arow = &aggL[dl * AGG_LD];
#pragma unroll
                    for (int nt = 0; nt < 2; ++nt) {
                        int c0 = nt * 16 + quad * 4;
#pragma unroll
                        for (int j = 0; j < 4; ++j) {
                            float v = acc2[ei2][nt][j] + sb2f[c0 + j];
                            v = (v > 0.f) ? v : 0.01f * v;
                            atomicMax(arow + c0 + j, fenc(bfr(v)));
                        }
                    }
                }
            }
            __syncthreads();
        }
        __syncthreads();   // covers cnt==0; aggL visible for finalize

        // finalize: out[node] = max(agg (empty->0), bf16(x[node]))
        {
            int nl = t >> 3, g4 = t & 7;
            int node = nodeBase + nl;
            if (node < N_NODES) {
                const unsigned* ar = &aggL[nl * AGG_LD + g4 * 4];
                float4 o;
                if constexpr (XB) {
                    ushort4 xw = ((const ushort4*)(xb + (size_t)node * IN_CH))[g4];
                    o.x = fmaxf((ar[0] == ENC_NEGINF) ? 0.f : fdec(ar[0]), __uint_as_float((unsigned)xw.x << 16));
                    o.y = fmaxf((ar[1] == ENC_NEGINF) ? 0.f : fdec(ar[1]), __uint_as_float((unsigned)xw.y << 16));
                    o.z = fmaxf((ar[2] == ENC_NEGINF) ? 0.f : fdec(ar[2]), __uint_as_float((unsigned)xw.z << 16));
                    o.w = fmaxf((ar[3] == ENC_NEGINF) ? 0.f : fdec(ar[3]), __uint_as_float((unsigned)xw.w << 16));
                } else {
                    float4 xv = ((const float4*)(x + (size_t)node * IN_CH))[g4];
                    o.x = fmaxf((ar[0] == ENC_NEGINF) ? 0.f : fdec(ar[0]), bfr(xv.x));
                    o.y = fmaxf((ar[1] == ENC_NEGINF) ? 0.f : fdec(ar[1]), bfr(xv.y));
                    o.z = fmaxf((ar[2] == ENC_NEGINF) ? 0.f : fdec(ar[2]), bfr(xv.z));
                    o.w = fmaxf((ar[3] == ENC_NEGINF) ? 0.f : fdec(ar[3]), bfr(xv.w));
                }
                ((float4*)(out + (size_t)node * OUT_CH))[g4] = o;
            }
        }
    }
}

// ================= fallback pipeline (round-2 structure, proven at 208-225 us) =================

__global__ __launch_bounds__(512) void coarse_bin(
    const int* __restrict__ ei, int nE, int* __restrict__ gSupCnt, int2* __restrict__ supRec,
    const float* __restrict__ W1, const float* __restrict__ b1,
    const float* __restrict__ W2, const float* __restrict__ b2,
    unsigned short* __restrict__ wsImg, float* __restrict__ wsb1, float* __restrict__ wsb2)
{
    __shared__ int cnt[256], wb[256], cur[256];
    const int t = threadIdx.x;
    if (blockIdx.x == 0) build_weight_image(W1, b1, W2, b2, wsImg, wsb1, wsb2, t, 512);
    if (t < 256) cnt[t] = 0;
    __syncthreads();

    const int lo = blockIdx.x * K1_EDGES;
    int rdst[K1_EPT], rsrc[K1_EPT];
#pragma unroll
    for (int k = 0; k < K1_EPT; ++k) {
        int e = lo + k * 512 + t;
        bool v = e < nE;
        rdst[k] = v ? __builtin_nontemporal_load(ei + nE + e) : -1;
        rsrc[k] = v ? __builtin_nontemporal_load(ei + e) : 0;
        if ((unsigned)rdst[k] >= N_NODES) rdst[k] = -1;
        if ((unsigned)rsrc[k] >= N_NODES) rsrc[k] = 0;
        if (rdst[k] >= 0) atomicAdd(&cnt[rdst[k] >> 9], 1);
    }
    __syncthreads();
    if (t < 256) {
        int c = cnt[t];
        wb[t] = c ? atomicAdd(&gSupCnt[t], c) : 0;
        cur[t] = 0;
    }
    __syncthreads();
#pragma unroll
    for (int k = 0; k < K1_EPT; ++k) {
        if (rdst[k] >= 0) {
            int s = rdst[k] >> 9;
            int pos = wb[s] + atomicAdd(&cur[s], 1);
            if (pos < CAP_SUP) {
                int e = lo + k * 512 + t;
                supRec[(size_t)s * CAP_SUP + pos] =
                    make_int2(rsrc[k], ((rdst[k] & 511) << 20) | e);
            }
        }
    }
}

__global__ __launch_bounds__(512) void fine_bin(
    const int* __restrict__ gSupCnt, const int2* __restrict__ supRec,
    int* __restrict__ gCnt, int2* __restrict__ rec,
    const float* __restrict__ x, unsigned short* __restrict__ xb)
{
    const int blk = blockIdx.x;
    const int s = blk >> 2, sl = blk & (K2_SPLIT - 1);
    const int t = threadIdx.x, lane = t & 63;

    if (xb) convert_x_bf16(x, xb, blk * 512 + t, NSUP * K2_SPLIT * 512);

    const int cntS = min(gSupCnt[s], CAP_SUP);
    const int lo = sl * K2_SLICE;
    const int hi = min(cntS, lo + K2_SLICE);

    int2 r[K2_SITERS];
#pragma unroll
    for (int k = 0; k < K2_SITERS; ++k) {
        int i = lo + k * 512 + t;
        r[k] = (i < hi) ? supRec[(size_t)s * CAP_SUP + i] : make_int2(0, 0);
    }
#pragma unroll
    for (int k = 0; k < K2_SITERS; ++k) {
        int i = lo + k * 512 + t;
        bool v = i < hi;
        int f = v ? ((r[k].y >> 26) & 7) : -1;
        int rank = 0, wbase = 0;
#pragma unroll
        for (int vv = 0; vv < 8; ++vv) {
            unsigned long long m = __ballot(f == vv);
            if (lane == vv) wbase = m ? atomicAdd(&gCnt[s * 8 + vv], (int)__popcll(m)) : 0;
            if (f == vv) rank = (int)__popcll(m & ((1ull << lane) - 1ull));
        }
        int base = __shfl(wbase, f & 7);
        if (v) {
            int pos = base + rank;
            if (pos < CAP)
                rec[(size_t)(s * 8 + f) * CAP + pos] =
                    make_int2(r[k].x, (((r[k].y >> 20) & 63) << 20) | (r[k].y & 0xFFFFF));
        }
    }
}

template<int XB>
__global__ __launch_bounds__(512, 4) void bucket_mlp(
    const float* __restrict__ x, const unsigned short* __restrict__ xb,
    const float* __restrict__ ea,
    const int2* __restrict__ rec, const int* __restrict__ gCnt,
    const unsigned short* __restrict__ wsImg,
    const float* __restrict__ wsb1, const float* __restrict__ wsb2,
    float* __restrict__ out)
{
    __shared__ unsigned short sFeatF[FEATF_SH];
    __shared__ unsigned short sWgt[WIMG_SH];
    __shared__ float sHdst[BKT_NODES * HSTRIDE];
    __shared__ unsigned aggL[BKT_NODES * AGG_LD];
    __shared__ float sb1f[64];
    __shared__ float sb2f[32];
    __shared__ int sdl[EPB];

    unsigned short* const sW1F = sWgt;
    unsigned short* const sW2F = sWgt + W1F_SH;
    unsigned short* const sW1D = sWgt + W1F_SH + W2F_SH;
    unsigned short* const sHF  = sFeatF;

    const int t = threadIdx.x;
    const int nodeBase = blockIdx.x << BKT_SHIFT;
    const int base = blockIdx.x * CAP;
    const int cnt  = min(gCnt[blockIdx.x], CAP);

    for (int i = t; i < WIMG_SH / 8; i += 512)
        *(short8*)&sWgt[i * 8] = *(const short8*)(wsImg + i * 8);
    for (int i = t; i < BKT_NODES * AGG_LD; i += 512) aggL[i] = ENC_NEGINF;
    if (t < 64) sb1f[t] = wsb1[t];
    else if (t < 96) sb2f[t - 64] = wsb2[t - 64];

    const int wave = t >> 6;
    const int l15  = t & 15;
    const int quad = (t & 63) >> 4;
    const int lane = t & 63;
    const int slot = t >> 1, q = t & 1;
    const int sl15 = slot & 15, set = slot >> 4;

    short8 rv16[4];
    int rdl;

    auto loadRec = [&](int idx) -> i32x2 {
        return (idx < cnt) ? *(const i32x2*)(rec + base + idx) : (i32x2){0, 0};
    };
    auto gather = [&](i32x2 r2, bool ok) {
        rdl = ok ? ((r2.y >> 20) & 63) : -1;
        short8 z = {0, 0, 0, 0, 0, 0, 0, 0};
        if (q == 0) {
            if constexpr (XB) {
                const short8* xs8 = (const short8*)(xb + (size_t)r2.x * IN_CH);
#pragma unroll
                for (int k = 0; k < 4; ++k) rv16[k] = ok ? xs8[k] : z;
            } else {
                const float* xs = x + (size_t)r2.x * IN_CH;
#pragma unroll
                for (int k = 0; k < 4; ++k)
                    rv16[k] = ok ? cvt8(((const float4*)xs)[2 * k], ((const float4*)xs)[2 * k + 1]) : z;
            }
        } else {
            const float* ep = ea + (size_t)(r2.y & 0xFFFFF) * EDGE_CH;
#pragma unroll
            for (int k = 0; k < 2; ++k)
                rv16[k] = ok ? cvt8(((const float4*)ep)[2 * k], ((const float4*)ep)[2 * k + 1]) : z;
            rv16[2] = z; rv16[3] = z;
        }
    };
    auto storeChunk = [&]() {
        if (q == 0) sdl[slot] = rdl;
#pragma unroll
        for (int k = 0; k < 4; ++k) {
            int cj = q * 4 + k;
            int a16 = (set * 2 + (cj >> 2)) * 64 + (cj & 3) * 16 + sl15;
            *(short8*)&sFeatF[a16 * 8] = rv16[k];
        }
    };

    i32x2 recC = loadRec(slot);
    i32x2 recN = loadRec(EPB + slot);
    gather(recC, slot < cnt);

    __syncthreads();

    {
        const int ntile = wave & 3, mh = wave >> 2;
        int node = nodeBase + ntile * 16 + l15;
        short8 bfr8 = {0, 0, 0, 0, 0, 0, 0, 0};
        if (node < N_NODES) {
            if constexpr (XB) {
                bfr8 = *(const short8*)(xb + (size_t)node * IN_CH + quad * 8);
            } else {
                const float* xp = x + (size_t)node * IN_CH + quad * 8;
                bfr8 = cvt8(((const float4*)xp)[0], ((const float4*)xp)[1]);
            }
        }
        f32x4 accd[2] = {(f32x4){0.f, 0.f, 0.f, 0.f}, (f32x4){0.f, 0.f, 0.f, 0.f}};
#pragma unroll
        for (int i = 0; i < 2; ++i) {
            int nt = mh * 2 + i;
            short8 af = *(const short8*)&sW1D[(nt * 64 + lane) * 8];
            accd[i] = __builtin_amdgcn_mfma_f32_16x16x32_bf16(af, bfr8, accd[i], 0, 0, 0);
        }
#pragma unroll
        for (int i = 0; i < 2; ++i) {
            int nt = mh * 2 + i, c0 = nt * 16 + quad * 4;
            float4 vv;
#pragma unroll
            for (int j = 0; j < 4; ++j) {
                int c = c0 + j;
                ((float*)&vv)[j] = (c < D_MID) ? accd[i][j] + sb1f[c] : 0.f;
            }
            *(float4*)&sHdst[(ntile * 16 + l15) * HSTRIDE + c0] = vv;
        }
    }

    for (int c0e = 0; c0e < cnt; c0e += EPB) {
        storeChunk();
        __syncthreads();
        gather(recN, (c0e + EPB + slot) < cnt);
        recN = loadRec(c0e + 2 * EPB + slot);

        f32x4 acc[2][4];
#pragma unroll
        for (int ei2 = 0; ei2 < 2; ++ei2)
#pragma unroll
            for (int nt = 0; nt < 4; ++nt) acc[ei2][nt] = (f32x4){0.f, 0.f, 0.f, 0.f};
#pragma unroll
        for (int ks = 0; ks < 2; ++ks) {
            short8 bf0 = *(const short8*)&sFeatF[((wave * 2 + ks) * 64 + lane) * 8];
            short8 bf1 = *(const short8*)&sFeatF[(((wave + 8) * 2 + ks) * 64 + lane) * 8];
#pragma unroll
            for (int nt = 0; nt < 4; ++nt) {
                short8 af = *(const short8*)&sW1F[((ks * 4 + nt) * 64 + lane) * 8];
                acc[0][nt] = __builtin_amdgcn_mfma_f32_16x16x32_bf16(af, bf0, acc[0][nt], 0, 0, 0);
                acc[1][nt] = __builtin_amdgcn_mfma_f32_16x16x32_bf16(af, bf1, acc[1][nt], 0, 0, 0);
            }
        }
        __syncthreads();

#pragma unroll
        for (int ei2 = 0; ei2 < 2; ++ei2) {
            int et = wave + ei2 * 8;
            int dl = sdl[et * 16 + l15];
            const float* hrow = &sHdst[((dl >= 0) ? dl : 0) * HSTRIDE];
#pragma unroll
            for (int nt = 0; nt < 4; ++nt) {
                int c0 = nt * 16 + quad * 4;
                float4 hd = *(const float4*)&hrow[c0];
                int ks2 = nt >> 1;
                int quad2 = (nt * 2 + (quad >> 1)) & 3;
                int off = (quad & 1) * 4;
                ushort4 p;
#pragma unroll
                for (int j = 0; j < 4; ++j) {
                    float v = acc[ei2][nt][j] + ((const float*)&hd)[j];
                    v = (v > 0.f) ? v : 0.01f * v;
                    ((unsigned short*)&p)[j] = (c0 + j < D_MID) ? bf16b(v) : (unsigned short)0;
                }
                *(ushort4*)&sHF[((et * 2 + ks2) * 64 + quad2 * 16 + l15) * 8 + off] = p;
            }
        }
        __syncthreads();

        f32x4 acc2[2][2];
#pragma unroll
        for (int ei2 = 0; ei2 < 2; ++ei2)
#pragma unroll
            for (int nt = 0; nt < 2; ++nt) acc2[ei2][nt] = (f32x4){0.f, 0.f, 0.f, 0.f};
#pragma unroll
        for (int ks = 0; ks < 2; ++ks) {
            short8 bf0 = *(const short8*)&sHF[((wave * 2 + ks) * 64 + lane) * 8];
            short8 bf1 = *(const short8*)&sHF[(((wave + 8) * 2 + ks) * 64 + lane) * 8];
#pragma unroll
            for (int nt = 0; nt < 2; ++nt) {
                short8 af = *(const short8*)&sW2F[((ks * 2 + nt) * 64 + lane) * 8];
                acc2[0][nt] = __builtin_amdgcn_mfma_f32_16x16x32_bf16(af, bf0, acc2[0][nt], 0, 0, 0);
                acc2[1][nt] = __builtin_amdgcn_mfma_f32_16x16x32_bf16(af, bf1, acc2[1][nt], 0, 0, 0);
            }
        }

#pragma unroll
        for (int ei2 = 0; ei2 < 2; ++ei2) {
            int et = wave + ei2 * 8;
            int dl = sdl[et * 16 + l15];
            if (dl >= 0) {
                unsigned* arow = &aggL[dl * AGG_LD];
#pragma unroll
                for (int nt = 0; nt < 2; ++nt) {
                    int c0 = nt * 16 + quad * 4;
#pragma unroll
                    for (int j = 0; j < 4; ++j) {
                        float v = acc2[ei2][nt][j] + sb2f[c0 + j];
                        v = (v > 0.f) ? v : 0.01f * v;
                        atomicMax(arow + c0 + j, fenc(bfr(v)));
                    }
                }
            }
        }
        __syncthreads();
    }
    __syncthreads();

    {
        int nl = t >> 3, g4 = t & 7;
        int node = nodeBase + nl;
        if (node < N_NODES) {
            const unsigned* ar = &aggL[nl * AGG_LD + g4 * 4];
            float4 o;
            if constexpr (XB) {
                ushort4 xw = ((const ushort4*)(xb + (size_t)node * IN_CH))[g4];
                o.x = fmaxf((ar[0] == ENC_NEGINF) ? 0.f : fdec(ar[0]), __uint_as_float((unsigned)xw.x << 16));
                o.y = fmaxf((ar[1] == ENC_NEGINF) ? 0.f : fdec(ar[1]), __uint_as_float((unsigned)xw.y << 16));
                o.z = fmaxf((ar[2] == ENC_NEGINF) ? 0.f : fdec(ar[2]), __uint_as_float((unsigned)xw.z << 16));
                o.w = fmaxf((ar[3] == ENC_NEGINF) ? 0.f : fdec(ar[3]), __uint_as_float((unsigned)xw.w << 16));
            } else {
                float4 xv = ((const float4*)(x + (size_t)node * IN_CH))[g4];
                o.x = fmaxf((ar[0] == ENC_NEGINF) ? 0.f : fdec(ar[0]), bfr(xv.x));
                o.y = fmaxf((ar[1] == ENC_NEGINF) ? 0.f : fdec(ar[1]), bfr(xv.y));
                o.z = fmaxf((ar[2] == ENC_NEGINF) ? 0.f : fdec(ar[2]), bfr(xv.z));
                o.w = fmaxf((ar[3] == ENC_NEGINF) ? 0.f : fdec(ar[3]), bfr(xv.w));
            }
            ((float4*)(out + (size_t)node * OUT_CH))[g4] = o;
        }
    }
}

__global__ __launch_bounds__(512) void scatter_append(
    const int* __restrict__ ei, int* __restrict__ gCnt, int2* __restrict__ rec, int nE,
    const float* __restrict__ W1, const float* __restrict__ b1,
    const float* __restrict__ W2, const float* __restrict__ b2,
    unsigned short* __restrict__ wsImg, float* __restrict__ wsb1, float* __restrict__ wsb2,
    const float* __restrict__ x, unsigned short* __restrict__ xb)
{
    __shared__ int lh[NB];
    __shared__ int lbase[NB];
    if (blockIdx.x == 0) build_weight_image(W1, b1, W2, b2, wsImg, wsb1, wsb2, threadIdx.x, 512);
    if (xb) convert_x_bf16(x, xb, blockIdx.x * 512 + threadIdx.x, gridDim.x * 512);
    for (int i = threadIdx.x; i < NB; i += 512) lh[i] = 0;
    __syncthreads();
    int per = (nE + gridDim.x - 1) / gridDim.x;
    int lo = blockIdx.x * per;
    int hi = min(lo + per, nE);
    for (int e = lo + threadIdx.x; e < hi; e += 512) {
        int dst = __builtin_nontemporal_load(ei + nE + e);
        if ((unsigned)dst < N_NODES) atomicAdd(&lh[dst >> BKT_SHIFT], 1);
    }
    __syncthreads();
    for (int i = threadIdx.x; i < NB; i += 512) {
        int c = lh[i];
        lbase[i] = c ? atomicAdd(&gCnt[i], c) : 0;
        lh[i] = 0;
    }
    __syncthreads();
    for (int e = lo + threadIdx.x; e < hi; e += 512) {
        int dst = __builtin_nontemporal_load(ei + nE + e);
        if ((unsigned)dst >= N_NODES) continue;
        int b = dst >> BKT_SHIFT;
        int p = lbase[b] + atomicAdd(&lh[b], 1);
        if (p >= CAP) continue;
        int src = __builtin_nontemporal_load(ei + e);
        if ((unsigned)src >= N_NODES) src = 0;
        rec[(size_t)b * CAP + p] = make_int2(src, ((dst & (BKT_NODES - 1)) << 20) | e);
    }
}

extern "C" void kernel_launch(void* const* d_in, const int* in_sizes, int n_in,
                              void* d_out, int out_size, void* d_ws, size_t ws_size,
                              hipStream_t stream) {
    const float* x  = (const float*)d_in[0];
    const int*   ei = (const int*)d_in[1];
    const float* ea = (const float*)d_in[2];
    const float* W1 = (const float*)d_in[3];
    const float* b1 = (const float*)d_in[4];
    const float* W2 = (const float*)d_in[5];
    const float* b2 = (const float*)d_in[6];

    char* ws = (char*)d_ws;
    unsigned short* wsImg = (unsigned short*)(ws + WS_IMG);
    float* wsb1 = (float*)(ws + WS_B1);
    float* wsb2 = (float*)(ws + WS_B2);
    int* gSupCnt = (int*)(ws + WS_SUPCNT);
    int* gCnt = (int*)(ws + WS_GCNT);

    const int nE = in_sizes[1] / 2;     // 1,000,000
    float* out = (float*)d_out;

    // ---- primary path: single fused cooperative kernel (tier-B ws layout) ----
    if (ws_size >= WS_NEED_B) {
        int2* rec = (int2*)(ws + 24576);
        bool xbOn = ws_size >= WS_NEED_BX;
        unsigned short* xb = xbOn ? (unsigned short*)(ws + WS_XB_B) : nullptr;
        hipMemsetAsync(gCnt, 0, NB_ALL * sizeof(int), stream);
        void* args[] = {(void*)&x, (void*)&xb, (void*)&ea, (void*)&ei, (void*)&nE,
                        (void*)&gCnt, (void*)&rec, (void*)&W1, (void*)&b1, (void*)&W2,
                        (void*)&b2, (void*)&wsImg, (void*)&wsb1, (void*)&wsb2, (void*)&out};
        const void* kfn = xbOn ? reinterpret_cast<const void*>(fused_all<1>)
                               : reinterpret_cast<const void*>(fused_all<0>);
        hipError_t err = hipLaunchCooperativeKernel(kfn, dim3(COOP_GRID), dim3(512),
                                                    args, 0, stream);
        if (err == hipSuccess) return;
        (void)hipGetLastError();   // clear sticky error; fall through to multi-kernel path
    }

    // ---- fallback: proven 3-kernel pipeline ----
    if (ws_size >= WS_NEED_A) {
        int2* supRec = (int2*)(ws + WS_SUPREC);
        int2* rec    = (int2*)(ws + WS_REC);
        bool xbOn = ws_size >= WS_NEED_AX;
        unsigned short* xb = xbOn ? (unsigned short*)(ws + WS_XB_A) : nullptr;
        hipMemsetAsync(ws + WS_Z0, 0, WS_ZSZ, stream);   // zero gSupCnt + gCnt
        coarse_bin<<<(nE + K1_EDGES - 1) / K1_EDGES, 512, 0, stream>>>(
            ei, nE, gSupCnt, supRec, W1, b1, W2, b2, wsImg, wsb1, wsb2);
        fine_bin<<<NSUP * K2_SPLIT, 512, 0, stream>>>(gSupCnt, supRec, gCnt, rec, x, xb);
        if (xbOn)
            bucket_mlp<1><<<NB, 512, 0, stream>>>(x, xb, ea, rec, gCnt, wsImg, wsb1, wsb2, out);
        else
            bucket_mlp<0><<<NB, 512, 0, stream>>>(x, nullptr, ea, rec, gCnt, wsImg, wsb1, wsb2, out);
    } else {
        int2* rec = (int2*)(ws + 24576);
        bool xbOn = ws_size >= WS_NEED_BX;
        unsigned short* xb = xbOn ? (unsigned short*)(ws + WS_XB_B) : nullptr;
        hipMemsetAsync(gCnt, 0, NB_ALL * sizeof(int), stream);
        scatter_append<<<128, 512, 0, stream>>>(ei, gCnt, rec, nE, W1, b1, W2, b2,
                                                wsImg, wsb1, wsb2, x, xb);
        if (xbOn)
            bucket_mlp<1><<<NB, 512, 0, stream>>>(x, xb, ea, rec, gCnt, wsImg, wsb1, wsb2, out);
        else
            bucket_mlp<0><<<NB, 512, 0, stream>>>(x, nullptr, ea, rec, gCnt, wsImg, wsb1, wsb2, out);
    }
}

// Round 7
// 248.175 us; speedup vs baseline: 1.1134x; 1.1134x over previous
//
#include <hip/hip_runtime.h>

#define N_NODES 100000
#define IN_CH 32
#define EDGE_CH 16
#define OUT_CH 32
#define D_CAT 80
#define D_MID 56

// fine buckets: 64 nodes each
#define BKT_SHIFT 6
#define BKT_NODES 64
#define NB 1563            // ceil(100000/64)
#define NB_ALL 1568        // padded
#define CAP 1024           // fine bucket capacity (mean 640, sd 25)

// super buckets: 512 nodes = 8 fine
#define NSUP 196
#define CAP_SUP 5632
#define K1_EDGES 2048      // 489 blocks
#define K1_EPT 4
#define K2_SPLIT 4         // 784 blocks
#define K2_SLICE 1408
#define K2_SITERS 3

#define EPB 256            // edges per chunk (512 threads: slot=t>>1, q=t&1)
#define NT_E 16

// fragment-major sizes (shorts)
#define W1F_SH 4096        // 2ks * 4nt * 64lane * 8   (K=64: src32 + ea16 + pad16)
#define W2F_SH 2048
#define W1D_SH 2048
#define WIMG_SH (W1F_SH + W2F_SH + W1D_SH)   // 16384 B
#define FEATF_SH (NT_E * 2 * 64 * 8)         // 32768 B (aliased by sHF)

#define HSTRIDE 68
#define AGG_LD 33
#define ENC_NEGINF 0x007FFFFFu

typedef short short8 __attribute__((ext_vector_type(8)));
typedef float f32x4 __attribute__((ext_vector_type(4)));
typedef int i32x2 __attribute__((ext_vector_type(2)));

// ---- ws layout (bytes) ----
#define WS_IMG    0
#define WS_B1     16384
#define WS_B2     16640
#define WS_SUPCNT 16768
#define WS_GCNT   17664                    // 1568*4
#define WS_Z0     16768
#define WS_ZSZ    (17664 + 6272 - 16768)   // 7168
#define WS_SUPREC 24576                    // 196*5632*8
#define WS_REC    8855552                  // 1568*1024*8
#define WS_XB_A   21700608                 // WS_REC + NB_ALL*CAP*8
#define XB_BYTES  6400000                  // 100000*32*2
#define WS_EB_A   (WS_XB_A + XB_BYTES)     // 28,100,608
#define EB_BYTES  ((size_t)NB_ALL * CAP * EDGE_CH * 2)    // 51,380,224
#define WS_NEED_A  ((size_t)WS_XB_A)                      // ~21.7 MB
#define WS_NEED_AX ((size_t)WS_XB_A + XB_BYTES)           // ~28.1 MB
#define WS_NEED_AE ((size_t)WS_EB_A + EB_BYTES)           // ~79.5 MB (binned bf16 ea)
// tier B: rec directly at 24576
#define WS_XB_B   12869632
#define WS_NEED_B  ((size_t)WS_XB_B)
#define WS_NEED_BX ((size_t)WS_XB_B + XB_BYTES)

__device__ __forceinline__ unsigned fenc(float f) {
    unsigned u = __float_as_uint(f);
    return (u & 0x80000000u) ? ~u : (u | 0x80000000u);
}
__device__ __forceinline__ float fdec(unsigned u) {
    u = (u & 0x80000000u) ? (u ^ 0x80000000u) : ~u;
    return __uint_as_float(u);
}
__device__ __forceinline__ float bfr(float f) {          // RNE to bf16 grid, as f32
    unsigned u = __float_as_uint(f);
    u = (u + 0x7FFFu + ((u >> 16) & 1u)) & 0xFFFF0000u;
    return __uint_as_float(u);
}
__device__ __forceinline__ unsigned short bf16b(float f) {  // RNE to bf16 bits
    unsigned u = __float_as_uint(f);
    return (unsigned short)((u + 0x7FFFu + ((u >> 16) & 1u)) >> 16);
}
__device__ __forceinline__ short8 cvt8(float4 a, float4 b) {
    return short8{ (short)bf16b(a.x), (short)bf16b(a.y), (short)bf16b(a.z), (short)bf16b(a.w),
                   (short)bf16b(b.x), (short)bf16b(b.y), (short)bf16b(b.z), (short)bf16b(b.w) };
}

__device__ __forceinline__ void convert_x_bf16(const float* __restrict__ x,
                                               unsigned short* __restrict__ xb,
                                               int gtid, int gstride) {
    const int tot = N_NODES * IN_CH / 8;   // 400000
    for (int i = gtid; i < tot; i += gstride) {
        float4 a = ((const float4*)x)[2 * i];
        float4 b = ((const float4*)x)[2 * i + 1];
        *(short8*)&xb[i * 8] = cvt8(a, b);
    }
}

// fragment-major weight images: W1F (K=64 src+ea), W2F, W1dF (dst rows of W1)
__device__ void build_weight_image(const float* __restrict__ W1, const float* __restrict__ b1,
                                   const float* __restrict__ W2, const float* __restrict__ b2,
                                   unsigned short* __restrict__ wsImg,
                                   float* __restrict__ wsb1, float* __restrict__ wsb2,
                                   int t, int nthr) {
    for (int s = t; s < W1F_SH; s += nthr) {
        int j = s & 7, l = (s >> 3) & 63, fi = s >> 9;
        int nt = fi & 3, ks = fi >> 2;
        int n = nt * 16 + (l & 15), kl = ks * 32 + (l >> 4) * 8 + j;
        unsigned short v = 0;
        if (n < D_MID) {
            if (kl < 32) v = bf16b(W1[kl * D_MID + n]);
            else if (kl < 48) v = bf16b(W1[(64 + kl - 32) * D_MID + n]);
        }
        wsImg[s] = v;
    }
    for (int s = t; s < W2F_SH; s += nthr) {
        int j = s & 7, l = (s >> 3) & 63, fi = s >> 9;
        int nt = fi & 1, ks = fi >> 1;
        int n = nt * 16 + (l & 15), kl = ks * 32 + (l >> 4) * 8 + j;
        wsImg[W1F_SH + s] = (kl < D_MID) ? bf16b(W2[kl * OUT_CH + n]) : (unsigned short)0;
    }
    for (int s = t; s < W1D_SH; s += nthr) {
        int j = s & 7, l = (s >> 3) & 63, fi = s >> 9;
        int nt = fi & 3;
        int n = nt * 16 + (l & 15), kl = (l >> 4) * 8 + j;
        wsImg[W1F_SH + W2F_SH + s] = (n < D_MID) ? bf16b(W1[(32 + kl) * D_MID + n]) : (unsigned short)0;
    }
    if (t < 64) wsb1[t] = (t < D_MID) ? bfr(b1[t]) : 0.f;
    else if (t < 96) wsb2[t - 64] = bfr(b2[t - 64]);
}

// ---------- K1: coarse bin (scan-free; proven R4) ----------
__global__ __launch_bounds__(512) void coarse_bin(
    const int* __restrict__ ei, int nE, int* __restrict__ gSupCnt, int2* __restrict__ supRec,
    const float* __restrict__ W1, const float* __restrict__ b1,
    const float* __restrict__ W2, const float* __restrict__ b2,
    unsigned short* __restrict__ wsImg, float* __restrict__ wsb1, float* __restrict__ wsb2)
{
    __shared__ int cnt[256], wb[256], cur[256];
    const int t = threadIdx.x;
    if (blockIdx.x == 0) build_weight_image(W1, b1, W2, b2, wsImg, wsb1, wsb2, t, 512);
    if (t < 256) cnt[t] = 0;
    __syncthreads();

    const int lo = blockIdx.x * K1_EDGES;
    int rdst[K1_EPT], rsrc[K1_EPT];
#pragma unroll
    for (int k = 0; k < K1_EPT; ++k) {
        int e = lo + k * 512 + t;
        bool v = e < nE;
        rdst[k] = v ? __builtin_nontemporal_load(ei + nE + e) : -1;
        rsrc[k] = v ? __builtin_nontemporal_load(ei + e) : 0;
        if ((unsigned)rdst[k] >= N_NODES) rdst[k] = -1;
        if ((unsigned)rsrc[k] >= N_NODES) rsrc[k] = 0;
        if (rdst[k] >= 0) atomicAdd(&cnt[rdst[k] >> 9], 1);
    }
    __syncthreads();
    if (t < 256) {
        int c = cnt[t];
        wb[t] = c ? atomicAdd(&gSupCnt[t], c) : 0;
        cur[t] = 0;
    }
    __syncthreads();
#pragma unroll
    for (int k = 0; k < K1_EPT; ++k) {
        if (rdst[k] >= 0) {
            int s = rdst[k] >> 9;
            int pos = wb[s] + atomicAdd(&cur[s], 1);
            if (pos < CAP_SUP) {
                int e = lo + k * 512 + t;
                supRec[(size_t)s * CAP_SUP + pos] =
                    make_int2(rsrc[k], ((rdst[k] & 511) << 20) | e);
            }
        }
    }
}

// ---------- K2: fine bin (ballot-rank) + binned-order bf16 edge-attr materialization ----------
// When eb != nullptr, each record's ea row is gathered here (64B-line gather, no barriers,
// huge TLP), converted to bf16 and written at eb[(bucket,pos)] -- ballot-rank gives
// consecutive pos per wave per bin, so writes land in ~256B runs. bucket_mlp then reads
// eb SEQUENTIALLY, eliminating its 64 MB random ea gather.
__global__ __launch_bounds__(512) void fine_bin(
    const int* __restrict__ gSupCnt, const int2* __restrict__ supRec,
    int* __restrict__ gCnt, int2* __restrict__ rec,
    const float* __restrict__ x, unsigned short* __restrict__ xb,
    const float* __restrict__ ea, unsigned short* __restrict__ eb)
{
    const int blk = blockIdx.x;
    const int s = blk >> 2, sl = blk & (K2_SPLIT - 1);
    const int t = threadIdx.x, lane = t & 63;

    if (xb) convert_x_bf16(x, xb, blk * 512 + t, NSUP * K2_SPLIT * 512);

    const int cntS = min(gSupCnt[s], CAP_SUP);
    const int lo = sl * K2_SLICE;
    const int hi = min(cntS, lo + K2_SLICE);

    int2 r[K2_SITERS];
#pragma unroll
    for (int k = 0; k < K2_SITERS; ++k) {
        int i = lo + k * 512 + t;
        r[k] = (i < hi) ? supRec[(size_t)s * CAP_SUP + i] : make_int2(0, 0);
    }
#pragma unroll
    for (int k = 0; k < K2_SITERS; ++k) {
        int i = lo + k * 512 + t;
        bool v = i < hi;
        int f = v ? ((r[k].y >> 26) & 7) : -1;
        int rank = 0, wbase = 0;
#pragma unroll
        for (int vv = 0; vv < 8; ++vv) {
            unsigned long long m = __ballot(f == vv);
            if (lane == vv) wbase = m ? atomicAdd(&gCnt[s * 8 + vv], (int)__popcll(m)) : 0;
            if (f == vv) rank = (int)__popcll(m & ((1ull << lane) - 1ull));
        }
        int base = __shfl(wbase, f & 7);
        if (v) {
            int pos = base + rank;
            if (pos < CAP) {
                size_t ridx = (size_t)(s * 8 + f) * CAP + pos;
                int e = r[k].y & 0xFFFFF;
                rec[ridx] = make_int2(r[k].x, (((r[k].y >> 20) & 63) << 20) | e);
                if (eb) {
                    const float4* ep = (const float4*)(ea + (size_t)e * EDGE_CH);
                    float4 a0 = ep[0];
                    float4 a1 = ep[1];
                    float4 a2 = ep[2];
                    float4 a3 = ep[3];
                    unsigned short* dst = eb + ridx * EDGE_CH;
                    *(short8*)dst = cvt8(a0, a1);
                    *(short8*)(dst + 8) = cvt8(a2, a3);
                }
            }
        }
    }
}

// ---------- tier B: single-kernel binning (scattered writes) ----------
__global__ __launch_bounds__(512) void scatter_append(
    const int* __restrict__ ei, int* __restrict__ gCnt, int2* __restrict__ rec, int nE,
    const float* __restrict__ W1, const float* __restrict__ b1,
    const float* __restrict__ W2, const float* __restrict__ b2,
    unsigned short* __restrict__ wsImg, float* __restrict__ wsb1, float* __restrict__ wsb2,
    const float* __restrict__ x, unsigned short* __restrict__ xb)
{
    __shared__ int lh[NB];
    __shared__ int lbase[NB];
    if (blockIdx.x == 0) build_weight_image(W1, b1, W2, b2, wsImg, wsb1, wsb2, threadIdx.x, 512);
    if (xb) convert_x_bf16(x, xb, blockIdx.x * 512 + threadIdx.x, gridDim.x * 512);
    for (int i = threadIdx.x; i < NB; i += 512) lh[i] = 0;
    __syncthreads();
    int per = (nE + gridDim.x - 1) / gridDim.x;
    int lo = blockIdx.x * per;
    int hi = min(lo + per, nE);
    for (int e = lo + threadIdx.x; e < hi; e += 512) {
        int dst = __builtin_nontemporal_load(ei + nE + e);
        if ((unsigned)dst < N_NODES) atomicAdd(&lh[dst >> BKT_SHIFT], 1);
    }
    __syncthreads();
    for (int i = threadIdx.x; i < NB; i += 512) {
        int c = lh[i];
        lbase[i] = c ? atomicAdd(&gCnt[i], c) : 0;
        lh[i] = 0;
    }
    __syncthreads();
    for (int e = lo + threadIdx.x; e < hi; e += 512) {
        int dst = __builtin_nontemporal_load(ei + nE + e);
        if ((unsigned)dst >= N_NODES) continue;
        int b = dst >> BKT_SHIFT;
        int p = lbase[b] + atomicAdd(&lh[b], 1);
        if (p >= CAP) continue;
        int src = __builtin_nontemporal_load(ei + e);
        if ((unsigned)src >= N_NODES) src = 0;
        rec[(size_t)b * CAP + p] = make_int2(src, ((dst & (BKT_NODES - 1)) << 20) | e);
    }
}

// ---------- main: per-bucket gather + MFMA MLP + LDS max + finalize ----------
// EB=1: edge attrs read sequentially from binned eb (no ea gather, no per-edge cvt).
template<int XB, int EB>
__global__ __launch_bounds__(512, 4) void bucket_mlp(
    const float* __restrict__ x, const unsigned short* __restrict__ xb,
    const float* __restrict__ ea, const unsigned short* __restrict__ eb,
    const int2* __restrict__ rec, const int* __restrict__ gCnt,
    const unsigned short* __restrict__ wsImg,
    const float* __restrict__ wsb1, const float* __restrict__ wsb2,
    float* __restrict__ out)
{
    __shared__ unsigned short sFeatF[FEATF_SH];   // 32768 B; aliased by sHF
    __shared__ unsigned short sWgt[WIMG_SH];      // 16384 B
    __shared__ float sHdst[BKT_NODES * HSTRIDE];  // 17408 B
    __shared__ unsigned aggL[BKT_NODES * AGG_LD]; //  8448 B
    __shared__ float sb1f[64];
    __shared__ float sb2f[32];
    __shared__ int sdl[EPB];                      //  1024 B

    unsigned short* const sW1F = sWgt;
    unsigned short* const sW2F = sWgt + W1F_SH;
    unsigned short* const sW1D = sWgt + W1F_SH + W2F_SH;
    unsigned short* const sHF  = sFeatF;

    const int t = threadIdx.x;
    const int nodeBase = blockIdx.x << BKT_SHIFT;
    const int base = blockIdx.x * CAP;
    const int cnt  = min(gCnt[blockIdx.x], CAP);

    for (int i = t; i < WIMG_SH / 8; i += 512)
        *(short8*)&sWgt[i * 8] = *(const short8*)(wsImg + i * 8);
    for (int i = t; i < BKT_NODES * AGG_LD; i += 512) aggL[i] = ENC_NEGINF;
    if (t < 64) sb1f[t] = wsb1[t];
    else if (t < 96) sb2f[t - 64] = wsb2[t - 64];

    const int wave = t >> 6;
    const int l15  = t & 15;
    const int quad = (t & 63) >> 4;
    const int lane = t & 63;
    const int slot = t >> 1, q = t & 1;
    const int sl15 = slot & 15, set = slot >> 4;

    short8 rv16[4];
    int rdl;

    auto loadRec = [&](int idx) -> i32x2 {
        return (idx < cnt) ? *(const i32x2*)(rec + base + idx) : (i32x2){0, 0};
    };
    // q=0: 4 src chunks (cols 0..31); q=1: 2 ea chunks (cols 32..47) + 2 zero pads
    auto gather = [&](i32x2 r2, int idx, bool ok) {
        rdl = ok ? ((r2.y >> 20) & 63) : -1;
        short8 z = {0, 0, 0, 0, 0, 0, 0, 0};
        if (q == 0) {
            if constexpr (XB) {
                const short8* xs8 = (const short8*)(xb + (size_t)r2.x * IN_CH);
#pragma unroll
                for (int k = 0; k < 4; ++k) rv16[k] = ok ? xs8[k] : z;
            } else {
                const float* xs = x + (size_t)r2.x * IN_CH;
#pragma unroll
                for (int k = 0; k < 4; ++k)
                    rv16[k] = ok ? cvt8(((const float4*)xs)[2 * k], ((const float4*)xs)[2 * k + 1]) : z;
            }
        } else {
            if constexpr (EB) {
                const short8* ep = (const short8*)(eb + (size_t)(base + idx) * EDGE_CH);
                rv16[0] = ok ? ep[0] : z;
                rv16[1] = ok ? ep[1] : z;
            } else {
                const float* ep = ea + (size_t)(r2.y & 0xFFFFF) * EDGE_CH;
#pragma unroll
                for (int k = 0; k < 2; ++k)
                    rv16[k] = ok ? cvt8(((const float4*)ep)[2 * k], ((const float4*)ep)[2 * k + 1]) : z;
            }
            rv16[2] = z; rv16[3] = z;
        }
    };
    auto storeChunk = [&]() {
        if (q == 0) sdl[slot] = rdl;
#pragma unroll
        for (int k = 0; k < 4; ++k) {
            int cj = q * 4 + k;
            int a16 = (set * 2 + (cj >> 2)) * 64 + (cj & 3) * 16 + sl15;
            *(short8*)&sFeatF[a16 * 8] = rv16[k];
        }
    };

    // prologue: rec 2 ahead, gathers 1 ahead
    i32x2 recC = loadRec(slot);
    i32x2 recN = loadRec(EPB + slot);
    gather(recC, slot, slot < cnt);

    __syncthreads();   // weight image + biases visible

    // per-node dst pre-GEMM: sHdst[node][c] = (W1d . x_dst)[c] + b1[c]
    {
        const int ntile = wave & 3, mh = wave >> 2;
        int node = nodeBase + ntile * 16 + l15;
        short8 bfr8 = {0, 0, 0, 0, 0, 0, 0, 0};
        if (node < N_NODES) {
            if constexpr (XB) {
                bfr8 = *(const short8*)(xb + (size_t)node * IN_CH + quad * 8);
            } else {
                const float* xp = x + (size_t)node * IN_CH + quad * 8;
                bfr8 = cvt8(((const float4*)xp)[0], ((const float4*)xp)[1]);
            }
        }
        f32x4 accd[2] = {(f32x4){0.f, 0.f, 0.f, 0.f}, (f32x4){0.f, 0.f, 0.f, 0.f}};
#pragma unroll
        for (int i = 0; i < 2; ++i) {
            int nt = mh * 2 + i;
            short8 af = *(const short8*)&sW1D[(nt * 64 + lane) * 8];
            accd[i] = __builtin_amdgcn_mfma_f32_16x16x32_bf16(af, bfr8, accd[i], 0, 0, 0);
        }
#pragma unroll
        for (int i = 0; i < 2; ++i) {
            int nt = mh * 2 + i, c0 = nt * 16 + quad * 4;
            float4 vv;
#pragma unroll
            for (int j = 0; j < 4; ++j) {
                int c = c0 + j;
                ((float*)&vv)[j] = (c < D_MID) ? accd[i][j] + sb1f[c] : 0.f;
            }
            *(float4*)&sHdst[(ntile * 16 + l15) * HSTRIDE + c0] = vv;
        }
    }

    for (int c0e = 0; c0e < cnt; c0e += EPB) {
        storeChunk();
        __syncthreads();
        gather(recN, c0e + EPB + slot, (c0e + EPB + slot) < cnt);
        recN = loadRec(c0e + 2 * EPB + slot);

        // GEMM1: K=64; each wave owns edge tiles {wave, wave+8}
        f32x4 acc[2][4];
#pragma unroll
        for (int ei2 = 0; ei2 < 2; ++ei2)
#pragma unroll
            for (int nt = 0; nt < 4; ++nt) acc[ei2][nt] = (f32x4){0.f, 0.f, 0.f, 0.f};
#pragma unroll
        for (int ks = 0; ks < 2; ++ks) {
            short8 bf0 = *(const short8*)&sFeatF[((wave * 2 + ks) * 64 + lane) * 8];
            short8 bf1 = *(const short8*)&sFeatF[(((wave + 8) * 2 + ks) * 64 + lane) * 8];
#pragma unroll
            for (int nt = 0; nt < 4; ++nt) {
                short8 af = *(const short8*)&sW1F[((ks * 4 + nt) * 64 + lane) * 8];
                acc[0][nt] = __builtin_amdgcn_mfma_f32_16x16x32_bf16(af, bf0, acc[0][nt], 0, 0, 0);
                acc[1][nt] = __builtin_amdgcn_mfma_f32_16x16x32_bf16(af, bf1, acc[1][nt], 0, 0, 0);
            }
        }
        __syncthreads();

        // epilogue1
#pragma unroll
        for (int ei2 = 0; ei2 < 2; ++ei2) {
            int et = wave + ei2 * 8;
            int dl = sdl[et * 16 + l15];
            const float* hrow = &sHdst[((dl >= 0) ? dl : 0) * HSTRIDE];
#pragma unroll
            for (int nt = 0; nt < 4; ++nt) {
                int c0 = nt * 16 + quad * 4;
                float4 hd = *(const float4*)&hrow[c0];
                int ks2 = nt >> 1;
                int quad2 = (nt * 2 + (quad >> 1)) & 3;
                int off = (quad & 1) * 4;
                ushort4 p;
#pragma unroll
                for (int j = 0; j < 4; ++j) {
                    float v = acc[ei2][nt][j] + ((const float*)&hd)[j];
                    v = (v > 0.f) ? v : 0.01f * v;
                    ((unsigned short*)&p)[j] = (c0 + j < D_MID) ? bf16b(v) : (unsigned short)0;
                }
                *(ushort4*)&sHF[((et * 2 + ks2) * 64 + quad2 * 16 + l15) * 8 + off] = p;
            }
        }
        __syncthreads();

        // GEMM2
        f32x4 acc2[2][2];
#pragma unroll
        for (int ei2 = 0; ei2 < 2; ++ei2)
#pragma unroll
            for (int nt = 0; nt < 2; ++nt) acc2[ei2][nt] = (f32x4){0.f, 0.f, 0.f, 0.f};
#pragma unroll
        for (int ks = 0; ks < 2; ++ks) {
            short8 bf0 = *(const short8*)&sHF[((wave * 2 + ks) * 64 + lane) * 8];
            short8 bf1 = *(const short8*)&sHF[(((wave + 8) * 2 + ks) * 64 + lane) * 8];
#pragma unroll
            for (int nt = 0; nt < 2; ++nt) {
                short8 af = *(const short8*)&sW2F[((ks * 2 + nt) * 64 + lane) * 8];
                acc2[0][nt] = __builtin_amdgcn_mfma_f32_16x16x32_bf16(af, bf0, acc2[0][nt], 0, 0, 0);
                acc2[1][nt] = __builtin_amdgcn_mfma_f32_16x16x32_bf16(af, bf1, acc2[1][nt], 0, 0, 0);
            }
        }

        // epilogue2: LDS scatter-max
#pragma unroll
        for (int ei2 = 0; ei2 < 2; ++ei2) {
            int et = wave + ei2 * 8;
            int dl = sdl[et * 16 + l15];
            if (dl >= 0) {
                unsigned* arow = &aggL[dl * AGG_LD];
#pragma unroll
                for (int nt = 0; nt < 2; ++nt) {
                    int c0 = nt * 16 + quad * 4;
#pragma unroll
                    for (int j = 0; j < 4; ++j) {
                        float v = acc2[ei2][nt][j] + sb2f[c0 + j];
                        v = (v > 0.f) ? v : 0.01f * v;
                        atomicMax(arow + c0 + j, fenc(bfr(v)));
                    }
                }
            }
        }
        __syncthreads();
    }
    __syncthreads();

    // finalize: out[node] = max(agg (empty->0), bf16(x[node]))
    {
        int nl = t >> 3, g4 = t & 7;
        int node = nodeBase + nl;
        if (node < N_NODES) {
            const unsigned* ar = &aggL[nl * AGG_LD + g4 * 4];
            float4 o;
            if constexpr (XB) {
                ushort4 xw = ((const ushort4*)(xb + (size_t)node * IN_CH))[g4];
                o.x = fmaxf((ar[0] == ENC_NEGINF) ? 0.f : fdec(ar[0]), __uint_as_float((unsigned)xw.x << 16));
                o.y = fmaxf((ar[1] == ENC_NEGINF) ? 0.f : fdec(ar[1]), __uint_as_float((unsigned)xw.y << 16));
                o.z = fmaxf((ar[2] == ENC_NEGINF) ? 0.f : fdec(ar[2]), __uint_as_float((unsigned)xw.z << 16));
                o.w = fmaxf((ar[3] == ENC_NEGINF) ? 0.f : fdec(ar[3]), __uint_as_float((unsigned)xw.w << 16));
            } else {
                float4 xv = ((const float4*)(x + (size_t)node * IN_CH))[g4];
                o.x = fmaxf((ar[0] == ENC_NEGINF) ? 0.f : fdec(ar[0]), bfr(xv.x));
                o.y = fmaxf((ar[1] == ENC_NEGINF) ? 0.f : fdec(ar[1]), bfr(xv.y));
                o.z = fmaxf((ar[2] == ENC_NEGINF) ? 0.f : fdec(ar[2]), bfr(xv.z));
                o.w = fmaxf((ar[3] == ENC_NEGINF) ? 0.f : fdec(ar[3]), bfr(xv.w));
            }
            ((float4*)(out + (size_t)node * OUT_CH))[g4] = o;
        }
    }
}

extern "C" void kernel_launch(void* const* d_in, const int* in_sizes, int n_in,
                              void* d_out, int out_size, void* d_ws, size_t ws_size,
                              hipStream_t stream) {
    const float* x  = (const float*)d_in[0];
    const int*   ei = (const int*)d_in[1];
    const float* ea = (const float*)d_in[2];
    const float* W1 = (const float*)d_in[3];
    const float* b1 = (const float*)d_in[4];
    const float* W2 = (const float*)d_in[5];
    const float* b2 = (const float*)d_in[6];

    char* ws = (char*)d_ws;
    unsigned short* wsImg = (unsigned short*)(ws + WS_IMG);
    float* wsb1 = (float*)(ws + WS_B1);
    float* wsb2 = (float*)(ws + WS_B2);
    int* gSupCnt = (int*)(ws + WS_SUPCNT);
    int* gCnt = (int*)(ws + WS_GCNT);

    const int nE = in_sizes[1] / 2;     // 1,000,000
    float* out = (float*)d_out;

    if (ws_size >= WS_NEED_A) {
        int2* supRec = (int2*)(ws + WS_SUPREC);
        int2* rec    = (int2*)(ws + WS_REC);
        bool xbOn = ws_size >= WS_NEED_AX;
        bool ebOn = ws_size >= WS_NEED_AE;
        unsigned short* xb = xbOn ? (unsigned short*)(ws + WS_XB_A) : nullptr;
        unsigned short* eb = ebOn ? (unsigned short*)(ws + WS_EB_A) : nullptr;
        hipMemsetAsync(ws + WS_Z0, 0, WS_ZSZ, stream);   // zero gSupCnt + gCnt
        coarse_bin<<<(nE + K1_EDGES - 1) / K1_EDGES, 512, 0, stream>>>(
            ei, nE, gSupCnt, supRec, W1, b1, W2, b2, wsImg, wsb1, wsb2);
        fine_bin<<<NSUP * K2_SPLIT, 512, 0, stream>>>(gSupCnt, supRec, gCnt, rec, x, xb, ea, eb);
        if (ebOn)
            bucket_mlp<1, 1><<<NB, 512, 0, stream>>>(x, xb, ea, eb, rec, gCnt, wsImg, wsb1, wsb2, out);
        else if (xbOn)
            bucket_mlp<1, 0><<<NB, 512, 0, stream>>>(x, xb, ea, nullptr, rec, gCnt, wsImg, wsb1, wsb2, out);
        else
            bucket_mlp<0, 0><<<NB, 512, 0, stream>>>(x, nullptr, ea, nullptr, rec, gCnt, wsImg, wsb1, wsb2, out);
    } else {
        // tier B: single scattered-write binning kernel
        int2* rec = (int2*)(ws + 24576);
        bool xbOn = ws_size >= WS_NEED_BX;
        unsigned short* xb = xbOn ? (unsigned short*)(ws + WS_XB_B) : nullptr;
        hipMemsetAsync(gCnt, 0, NB_ALL * sizeof(int), stream);
        scatter_append<<<128, 512, 0, stream>>>(ei, gCnt, rec, nE, W1, b1, W2, b2,
                                                wsImg, wsb1, wsb2, x, xb);
        if (xbOn)
            bucket_mlp<1, 0><<<NB, 512, 0, stream>>>(x, xb, ea, nullptr, rec, gCnt, wsImg, wsb1, wsb2, out);
        else
            bucket_mlp<0, 0><<<NB, 512, 0, stream>>>(x, nullptr, ea, nullptr, rec, gCnt, wsImg, wsb1, wsb2, out);
    }
}

// Round 8
// 208.517 us; speedup vs baseline: 1.3251x; 1.1902x over previous
//
#include <hip/hip_runtime.h>

#define N_NODES 100000
#define IN_CH 32
#define EDGE_CH 16
#define OUT_CH 32
#define D_CAT 80
#define D_MID 56

// fine buckets: 64 nodes each
#define BKT_SHIFT 6
#define BKT_NODES 64
#define NB 1563            // ceil(100000/64), used by bucket_mlp grid
#define NB_ALL 1568        // 196 supers * 8 fines (padded)
#define CAP 1024           // fine bucket capacity (mean 640, sd 25)

// super buckets: 512 nodes = 8 fine
#define NSUP 196
#define CAP_SUP 5632       // mean 5120, sd 71 -> +7.2 sigma
#define K1_EDGES 4096
#define K2_ITERS 11        // ceil(5632/512)

#define EPB 256            // edges per chunk (512 threads: slot=t>>1, q=t&1)
#define NT_E 16            // edge tiles (16 edges each) per chunk

// fragment-major sizes (shorts)
#define W1F_SH 4096        // 2ks * 4nt * 64lane * 8   (K=64: src32 + ea16 + pad16)
#define W2F_SH 2048        // 2ks * 2nt * 64lane * 8
#define W1D_SH 2048        // 1ks * 4nt * 64lane * 8   (dst rows 32..63 of W1)
#define WIMG_SH (W1F_SH + W2F_SH + W1D_SH)   // 8192 shorts = 16384 B
#define FEATF_SH (NT_E * 2 * 64 * 8)         // 16384 shorts = 32768 B (aliased by sHF)

#define HSTRIDE 68         // f32 stride of hdstPre rows (bank spread + float4 aligned)
#define AGG_LD 33
#define ENC_NEGINF 0x007FFFFFu

typedef short short8 __attribute__((ext_vector_type(8)));
typedef float f32x4 __attribute__((ext_vector_type(4)));
typedef int i32x2 __attribute__((ext_vector_type(2)));

// ---- ws layout (bytes) ----
#define WS_IMG    0
#define WS_B1     16384
#define WS_B2     16640
#define WS_SUPCNT 16768                    // 196*4 = 784
#define WS_GCNT   17664                    // 1568*4 = 6272
#define WS_SUPREC 24576                    // 196*5632*8 = 8,830,976
#define WS_REC    8855552                  // 1568*1024*8 = 12,845,056
#define WS_XB_A   21700608                 // WS_REC + NB_ALL*CAP*8
#define XB_BYTES  6400000                  // 100000*32*2
#define WS_NEED_A ((size_t)WS_XB_A)                       // ~21.7 MB (f32 fallback)
#define WS_NEED_AX ((size_t)WS_XB_A + XB_BYTES)           // ~28.1 MB (bf16 x)
// tier B: rec directly at 24576
#define WS_XB_B   12869632                 // 24576 + NB_ALL*CAP*8
#define WS_NEED_B ((size_t)WS_XB_B)                       // ~12.9 MB
#define WS_NEED_BX ((size_t)WS_XB_B + XB_BYTES)           // ~19.3 MB

__device__ __forceinline__ unsigned fenc(float f) {
    unsigned u = __float_as_uint(f);
    return (u & 0x80000000u) ? ~u : (u | 0x80000000u);
}
__device__ __forceinline__ float fdec(unsigned u) {
    u = (u & 0x80000000u) ? (u ^ 0x80000000u) : ~u;
    return __uint_as_float(u);
}
__device__ __forceinline__ float bfr(float f) {          // RNE to bf16 grid, as f32
    unsigned u = __float_as_uint(f);
    u = (u + 0x7FFFu + ((u >> 16) & 1u)) & 0xFFFF0000u;
    return __uint_as_float(u);
}
__device__ __forceinline__ unsigned short bf16b(float f) {  // RNE to bf16 bits
    unsigned u = __float_as_uint(f);
    return (unsigned short)((u + 0x7FFFu + ((u >> 16) & 1u)) >> 16);
}
__device__ __forceinline__ short8 cvt8(float4 a, float4 b) {
    return short8{ (short)bf16b(a.x), (short)bf16b(a.y), (short)bf16b(a.z), (short)bf16b(a.w),
                   (short)bf16b(b.x), (short)bf16b(b.y), (short)bf16b(b.z), (short)bf16b(b.w) };
}

// grid-stride f32 -> bf16 conversion of x (short8 granules)
__device__ __forceinline__ void convert_x_bf16(const float* __restrict__ x,
                                               unsigned short* __restrict__ xb,
                                               int gtid, int gstride) {
    const int tot = N_NODES * IN_CH / 8;   // 400000
    for (int i = gtid; i < tot; i += gstride) {
        float4 a = ((const float4*)x)[2 * i];
        float4 b = ((const float4*)x)[2 * i + 1];
        *(short8*)&xb[i * 8] = cvt8(a, b);
    }
}

// fragment-major weight images:
//  W1F  [0,4096):      A-frags for GEMM1, K=64 = [src rows 0..31 | ea rows 64..79 | pad]
//  W2F  [4096,6144):   A-frags for GEMM2, K=64 = [W2 rows 0..55 | pad]
//  W1dF [6144,8192):   A-frags for per-node dst GEMM, K=32 = W1 rows 32..63
__device__ void build_weight_image(const float* __restrict__ W1, const float* __restrict__ b1,
                                   const float* __restrict__ W2, const float* __restrict__ b2,
                                   unsigned short* __restrict__ wsImg,
                                   float* __restrict__ wsb1, float* __restrict__ wsb2,
                                   int t, int nthr) {
    for (int s = t; s < W1F_SH; s += nthr) {
        int j = s & 7, l = (s >> 3) & 63, fi = s >> 9;     // fi 0..7
        int nt = fi & 3, ks = fi >> 2;                      // ks 0..1
        int n = nt * 16 + (l & 15), kl = ks * 32 + (l >> 4) * 8 + j;   // kl 0..63
        unsigned short v = 0;
        if (n < D_MID) {
            if (kl < 32) v = bf16b(W1[kl * D_MID + n]);                       // src
            else if (kl < 48) v = bf16b(W1[(64 + kl - 32) * D_MID + n]);      // ea
        }
        wsImg[s] = v;
    }
    for (int s = t; s < W2F_SH; s += nthr) {
        int j = s & 7, l = (s >> 3) & 63, fi = s >> 9;     // fi 0..3
        int nt = fi & 1, ks = fi >> 1;
        int n = nt * 16 + (l & 15), kl = ks * 32 + (l >> 4) * 8 + j;
        wsImg[W1F_SH + s] = (kl < D_MID) ? bf16b(W2[kl * OUT_CH + n]) : (unsigned short)0;
    }
    for (int s = t; s < W1D_SH; s += nthr) {
        int j = s & 7, l = (s >> 3) & 63, fi = s >> 9;     // fi 0..3
        int nt = fi & 3;                                    // ks = 0
        int n = nt * 16 + (l & 15), kl = (l >> 4) * 8 + j;  // kl 0..31 -> W1 row 32+kl
        wsImg[W1F_SH + W2F_SH + s] = (n < D_MID) ? bf16b(W1[(32 + kl) * D_MID + n]) : (unsigned short)0;
    }
    if (t < 64) wsb1[t] = (t < D_MID) ? bfr(b1[t]) : 0.f;
    else if (t < 96) wsb2[t - 64] = bfr(b2[t - 64]);
}

// ---------- K1: coarse bin (4096-edge tiles -> 196 super-buckets, coalesced flush) ----------
// R2-proven variant: LDS histogram + prefix scan + staged coalesced flush.
__global__ __launch_bounds__(512) void coarse_bin(
    const int* __restrict__ ei, int nE, int* __restrict__ gSupCnt, int2* __restrict__ supRec,
    const float* __restrict__ W1, const float* __restrict__ b1,
    const float* __restrict__ W2, const float* __restrict__ b2,
    unsigned short* __restrict__ wsImg, float* __restrict__ wsb1, float* __restrict__ wsb2)
{
    __shared__ int2 staged[K1_EDGES];             // 32 KB
    __shared__ int cnt[256], sc[256], cur[256], wb[256];
    const int t = threadIdx.x;
    if (blockIdx.x == 0) build_weight_image(W1, b1, W2, b2, wsImg, wsb1, wsb2, t, 512);
    if (t < 256) cnt[t] = 0;
    __syncthreads();

    const int lo = blockIdx.x * K1_EDGES;
    int rdst[8], rsrc[8];
#pragma unroll
    for (int k = 0; k < 8; ++k) {
        int e = lo + k * 512 + t;
        bool v = e < nE;
        rdst[k] = v ? __builtin_nontemporal_load(ei + nE + e) : -1;
        rsrc[k] = v ? __builtin_nontemporal_load(ei + e) : 0;
        if ((unsigned)rdst[k] >= N_NODES) rdst[k] = -1;
        if ((unsigned)rsrc[k] >= N_NODES) rsrc[k] = 0;
        if (rdst[k] >= 0) atomicAdd(&cnt[rdst[k] >> 9], 1);
    }
    __syncthreads();
    if (t < 256) sc[t] = cnt[t];
    __syncthreads();
    for (int off = 1; off < 256; off <<= 1) {
        int v = 0;
        if (t < 256 && t >= off) v = sc[t - off];
        __syncthreads();
        if (t < 256) sc[t] += v;
        __syncthreads();
    }
    if (t < NSUP) {
        int c = cnt[t];
        int excl = sc[t] - c;
        int g = c ? atomicAdd(&gSupCnt[t], c) : 0;
        wb[t] = t * CAP_SUP + g - excl;
        cur[t] = excl;
    }
    __syncthreads();
#pragma unroll
    for (int k = 0; k < 8; ++k) {
        if (rdst[k] >= 0) {
            int s = rdst[k] >> 9;
            int pos = atomicAdd(&cur[s], 1);
            int e = lo + k * 512 + t;
            staged[pos] = make_int2(rsrc[k] | (s << 24), ((rdst[k] & 511) << 20) | e);
        }
    }
    __syncthreads();
    int nv = sc[NSUP - 1];   // total valid edges staged
    for (int i = t; i < nv; i += 512) {
        int2 r = staged[i];
        int s = (unsigned)r.x >> 24;
        int addr = wb[s] + i;
        if (addr - s * CAP_SUP < CAP_SUP)
            supRec[addr] = make_int2(r.x & 0x00FFFFFF, r.y);
    }
}

// ---------- K2: fine bin (ballot-rank single pass, direct rec writes; R2-proven) ----------
__global__ __launch_bounds__(512) void fine_bin(
    const int* __restrict__ gSupCnt, const int2* __restrict__ supRec,
    int* __restrict__ gCnt, int2* __restrict__ rec,
    const float* __restrict__ x, unsigned short* __restrict__ xb)
{
    __shared__ int cur8[8];
    const int s = blockIdx.x, t = threadIdx.x;
    const int lane = t & 63;

    if (xb) convert_x_bf16(x, xb, s * 512 + t, NSUP * 512);

    const int cntS = min(gSupCnt[s], CAP_SUP);
    if (t < 8) cur8[t] = 0;
    __syncthreads();

    int2 r[K2_ITERS];
#pragma unroll
    for (int k = 0; k < K2_ITERS; ++k) {
        int i = k * 512 + t;
        r[k] = (i < cntS) ? supRec[(size_t)s * CAP_SUP + i] : make_int2(0, 0);
    }
#pragma unroll
    for (int k = 0; k < K2_ITERS; ++k) {
        int i = k * 512 + t;
        bool v = i < cntS;
        int f = v ? ((r[k].y >> 26) & 7) : -1;
        int rank = 0, wbase = 0;
#pragma unroll
        for (int vv = 0; vv < 8; ++vv) {
            unsigned long long m = __ballot(f == vv);
            if (lane == vv) wbase = m ? atomicAdd(&cur8[vv], (int)__popcll(m)) : 0;
            if (f == vv) rank = (int)__popcll(m & ((1ull << lane) - 1ull));
        }
        int base = __shfl(wbase, f & 7);
        if (v) {
            int pos = base + rank;
            if (pos < CAP)
                rec[(size_t)(s * 8 + f) * CAP + pos] =
                    make_int2(r[k].x, (((r[k].y >> 20) & 63) << 20) | (r[k].y & 0xFFFFF));
        }
    }
    __syncthreads();
    if (t < 8) gCnt[s * 8 + t] = min(cur8[t], CAP);
}

// ---------- tier B: single-kernel binning (scattered writes), exact same rec format ----------
__global__ __launch_bounds__(512) void scatter_append(
    const int* __restrict__ ei, int* __restrict__ gCnt, int2* __restrict__ rec, int nE,
    const float* __restrict__ W1, const float* __restrict__ b1,
    const float* __restrict__ W2, const float* __restrict__ b2,
    unsigned short* __restrict__ wsImg, float* __restrict__ wsb1, float* __restrict__ wsb2,
    const float* __restrict__ x, unsigned short* __restrict__ xb)
{
    __shared__ int lh[NB];
    __shared__ int lbase[NB];
    if (blockIdx.x == 0) build_weight_image(W1, b1, W2, b2, wsImg, wsb1, wsb2, threadIdx.x, 512);
    if (xb) convert_x_bf16(x, xb, blockIdx.x * 512 + threadIdx.x, gridDim.x * 512);
    for (int i = threadIdx.x; i < NB; i += 512) lh[i] = 0;
    __syncthreads();
    int per = (nE + gridDim.x - 1) / gridDim.x;
    int lo = blockIdx.x * per;
    int hi = min(lo + per, nE);
    for (int e = lo + threadIdx.x; e < hi; e += 512) {
        int dst = __builtin_nontemporal_load(ei + nE + e);
        if ((unsigned)dst < N_NODES) atomicAdd(&lh[dst >> BKT_SHIFT], 1);
    }
    __syncthreads();
    for (int i = threadIdx.x; i < NB; i += 512) {
        int c = lh[i];
        lbase[i] = c ? atomicAdd(&gCnt[i], c) : 0;
        lh[i] = 0;
    }
    __syncthreads();
    for (int e = lo + threadIdx.x; e < hi; e += 512) {
        int dst = __builtin_nontemporal_load(ei + nE + e);
        if ((unsigned)dst >= N_NODES) continue;
        int b = dst >> BKT_SHIFT;
        int p = lbase[b] + atomicAdd(&lh[b], 1);
        if (p >= CAP) continue;
        int src = __builtin_nontemporal_load(ei + e);
        if ((unsigned)src >= N_NODES) src = 0;
        rec[(size_t)b * CAP + p] = make_int2(src, ((dst & (BKT_NODES - 1)) << 20) | e);
    }
}

// ---------- main: per-bucket gather + MFMA MLP + LDS max + finalize ----------
// R2-proven structure (77.5 us). Round-8 change: ep2 atomics carry fenc(raw f32) --
// bfr (RNE to bf16) is monotone, so max(bfr(v)) == bfr(max(v)); apply bfr ONCE in
// finalize instead of 16x per thread per chunk. Output bits unchanged.
template<int XB>
__global__ __launch_bounds__(512, 4) void bucket_mlp(
    const float* __restrict__ x, const unsigned short* __restrict__ xb,
    const float* __restrict__ ea,
    const int2* __restrict__ rec, const int* __restrict__ gCnt,
    const unsigned short* __restrict__ wsImg,
    const float* __restrict__ wsb1, const float* __restrict__ wsb2,
    float* __restrict__ out)
{
    __shared__ unsigned short sFeatF[FEATF_SH];   // 32768 B; aliased by sHF
    __shared__ unsigned short sWgt[WIMG_SH];      // 16384 B (W1F | W2F | W1dF)
    __shared__ float sHdst[BKT_NODES * HSTRIDE];  // 17408 B (W1d·x_dst + b1, f32)
    __shared__ unsigned aggL[BKT_NODES * AGG_LD]; //  8448 B
    __shared__ float sb1f[64];
    __shared__ float sb2f[32];
    __shared__ int sdl[EPB];                      //  1024 B

    unsigned short* const sW1F = sWgt;
    unsigned short* const sW2F = sWgt + W1F_SH;
    unsigned short* const sW1D = sWgt + W1F_SH + W2F_SH;
    unsigned short* const sHF  = sFeatF;          // alias (exact same extent)

    const int t = threadIdx.x;
    const int nodeBase = blockIdx.x << BKT_SHIFT;
    const int base = blockIdx.x * CAP;
    const int cnt  = min(gCnt[blockIdx.x], CAP);

    for (int i = t; i < WIMG_SH / 8; i += 512)
        *(short8*)&sWgt[i * 8] = *(const short8*)(wsImg + i * 8);
    for (int i = t; i < BKT_NODES * AGG_LD; i += 512) aggL[i] = ENC_NEGINF;
    if (t < 64) sb1f[t] = wsb1[t];
    else if (t < 96) sb2f[t - 64] = wsb2[t - 64];

    const int wave = t >> 6;
    const int l15  = t & 15;
    const int quad = (t & 63) >> 4;
    const int lane = t & 63;
    const int slot = t >> 1, q = t & 1;
    const int sl15 = slot & 15, set = slot >> 4;   // set: edge tile 0..15

    short8 rv16[4];
    int rdl;

    auto loadRec = [&](int idx) -> i32x2 {
        return (idx < cnt) ? *(const i32x2*)(rec + base + idx) : (i32x2){0, 0};
    };
    // q=0: 4 src chunks (cols 0..31); q=1: 2 ea chunks (cols 32..47) + 2 zero pads
    auto gather = [&](i32x2 r2, bool ok) {
        rdl = ok ? ((r2.y >> 20) & 63) : -1;
        short8 z = {0, 0, 0, 0, 0, 0, 0, 0};
        if (q == 0) {
            if constexpr (XB) {
                const short8* xs8 = (const short8*)(xb + (size_t)r2.x * IN_CH);
#pragma unroll
                for (int k = 0; k < 4; ++k) rv16[k] = ok ? xs8[k] : z;
            } else {
                const float* xs = x + (size_t)r2.x * IN_CH;
#pragma unroll
                for (int k = 0; k < 4; ++k)
                    rv16[k] = ok ? cvt8(((const float4*)xs)[2 * k], ((const float4*)xs)[2 * k + 1]) : z;
            }
        } else {
            const float* ep = ea + (size_t)(r2.y & 0xFFFFF) * EDGE_CH;
#pragma unroll
            for (int k = 0; k < 2; ++k)
                rv16[k] = ok ? cvt8(((const float4*)ep)[2 * k], ((const float4*)ep)[2 * k + 1]) : z;
            rv16[2] = z; rv16[3] = z;
        }
    };
    auto storeChunk = [&]() {
        if (q == 0) sdl[slot] = rdl;
#pragma unroll
        for (int k = 0; k < 4; ++k) {
            int cj = q * 4 + k;
            int a16 = (set * 2 + (cj >> 2)) * 64 + (cj & 3) * 16 + sl15;
            *(short8*)&sFeatF[a16 * 8] = rv16[k];
        }
    };

    // prologue: rec 2 ahead, gathers 1 ahead (all global, no LDS dependency)
    i32x2 recC = loadRec(slot);
    i32x2 recN = loadRec(EPB + slot);
    gather(recC, slot < cnt);

    __syncthreads();   // weight image + biases visible

    // per-node dst pre-GEMM: hdstPre[node][c] = (W1d · x_dst)[c] + b1[c]  (c < 56, else 0)
    {
        const int ntile = wave & 3, mh = wave >> 2;
        int node = nodeBase + ntile * 16 + l15;
        short8 bfr8 = {0, 0, 0, 0, 0, 0, 0, 0};
        if (node < N_NODES) {
            if constexpr (XB) {
                bfr8 = *(const short8*)(xb + (size_t)node * IN_CH + quad * 8);
            } else {
                const float* xp = x + (size_t)node * IN_CH + quad * 8;
                bfr8 = cvt8(((const float4*)xp)[0], ((const float4*)xp)[1]);
            }
        }
        f32x4 accd[2] = {(f32x4){0.f, 0.f, 0.f, 0.f}, (f32x4){0.f, 0.f, 0.f, 0.f}};
#pragma unroll
        for (int i = 0; i < 2; ++i) {
            int nt = mh * 2 + i;
            short8 af = *(const short8*)&sW1D[(nt * 64 + lane) * 8];
            accd[i] = __builtin_amdgcn_mfma_f32_16x16x32_bf16(af, bfr8, accd[i], 0, 0, 0);
        }
#pragma unroll
        for (int i = 0; i < 2; ++i) {
            int nt = mh * 2 + i, c0 = nt * 16 + quad * 4;
            float4 vv;
#pragma unroll
            for (int j = 0; j < 4; ++j) {
                int c = c0 + j;
                ((float*)&vv)[j] = (c < D_MID) ? accd[i][j] + sb1f[c] : 0.f;
            }
            *(float4*)&sHdst[(ntile * 16 + l15) * HSTRIDE + c0] = vv;
        }
    }
    // no barrier needed: each wave's sHdst writes precede its loop barriers; first
    // ep1 read happens after two in-loop __syncthreads.

    for (int c0e = 0; c0e < cnt; c0e += EPB) {
        storeChunk();
        __syncthreads();
        // issue next chunk's gathers now -> latency hidden by GEMM1+ep1+GEMM2
        gather(recN, (c0e + EPB + slot) < cnt);
        recN = loadRec(c0e + 2 * EPB + slot);

        // GEMM1: D[m=h_col][n=edge], K=64; each wave owns edge tiles {wave, wave+8}
        f32x4 acc[2][4];
#pragma unroll
        for (int ei = 0; ei < 2; ++ei)
#pragma unroll
            for (int nt = 0; nt < 4; ++nt) acc[ei][nt] = (f32x4){0.f, 0.f, 0.f, 0.f};
#pragma unroll
        for (int ks = 0; ks < 2; ++ks) {
            short8 bf0 = *(const short8*)&sFeatF[((wave * 2 + ks) * 64 + lane) * 8];
            short8 bf1 = *(const short8*)&sFeatF[(((wave + 8) * 2 + ks) * 64 + lane) * 8];
#pragma unroll
            for (int nt = 0; nt < 4; ++nt) {
                short8 af = *(const short8*)&sW1F[((ks * 4 + nt) * 64 + lane) * 8];
                acc[0][nt] = __builtin_amdgcn_mfma_f32_16x16x32_bf16(af, bf0, acc[0][nt], 0, 0, 0);
                acc[1][nt] = __builtin_amdgcn_mfma_f32_16x16x32_bf16(af, bf1, acc[1][nt], 0, 0, 0);
            }
        }
        __syncthreads();   // sFeatF reads done before aliased sHF writes

        // epilogue1: add hdstPre[dl] (has b1), LeakyReLU, -> fragment-major sHF
#pragma unroll
        for (int ei = 0; ei < 2; ++ei) {
            int et = wave + ei * 8;
            int dl = sdl[et * 16 + l15];
            const float* hrow = &sHdst[((dl >= 0) ? dl : 0) * HSTRIDE];
#pragma unroll
            for (int nt = 0; nt < 4; ++nt) {
                int c0 = nt * 16 + quad * 4;
                float4 hd = *(const float4*)&hrow[c0];
                int ks2 = nt >> 1;
                int quad2 = (nt * 2 + (quad >> 1)) & 3;
                int off = (quad & 1) * 4;
                ushort4 p;
#pragma unroll
                for (int j = 0; j < 4; ++j) {
                    float v = acc[ei][nt][j] + ((const float*)&hd)[j];
                    v = (v > 0.f) ? v : 0.01f * v;
                    ((unsigned short*)&p)[j] = (c0 + j < D_MID) ? bf16b(v) : (unsigned short)0;
                }
                *(ushort4*)&sHF[((et * 2 + ks2) * 64 + quad2 * 16 + l15) * 8 + off] = p;
            }
        }
        __syncthreads();

        // GEMM2: D[m=out_col][n=edge], K=64
        f32x4 acc2[2][2];
#pragma unroll
        for (int ei = 0; ei < 2; ++ei)
#pragma unroll
            for (int nt = 0; nt < 2; ++nt) acc2[ei][nt] = (f32x4){0.f, 0.f, 0.f, 0.f};
#pragma unroll
        for (int ks = 0; ks < 2; ++ks) {
            short8 bf0 = *(const short8*)&sHF[((wave * 2 + ks) * 64 + lane) * 8];
            short8 bf1 = *(const short8*)&sHF[(((wave + 8) * 2 + ks) * 64 + lane) * 8];
#pragma unroll
            for (int nt = 0; nt < 2; ++nt) {
                short8 af = *(const short8*)&sW2F[((ks * 2 + nt) * 64 + lane) * 8];
                acc2[0][nt] = __builtin_amdgcn_mfma_f32_16x16x32_bf16(af, bf0, acc2[0][nt], 0, 0, 0);
                acc2[1][nt] = __builtin_amdgcn_mfma_f32_16x16x32_bf16(af, bf1, acc2[1][nt], 0, 0, 0);
            }
        }

        // epilogue2: LDS scatter-max on RAW f32 order-encoding (bfr deferred to finalize)
#pragma unroll
        for (int ei = 0; ei < 2; ++ei) {
            int et = wave + ei * 8;
            int dl = sdl[et * 16 + l15];
            if (dl >= 0) {
                unsigned* arow = &aggL[dl * AGG_LD];
#pragma unroll
                for (int nt = 0; nt < 2; ++nt) {
                    int c0 = nt * 16 + quad * 4;
#pragma unroll
                    for (int j = 0; j < 4; ++j) {
                        float v = acc2[ei][nt][j] + sb2f[c0 + j];
                        v = (v > 0.f) ? v : 0.01f * v;
                        atomicMax(arow + c0 + j, fenc(v));
                    }
                }
            }
        }
        __syncthreads();   // atomics + sHF reads done before next storeChunk
    }
    __syncthreads();       // covers cnt==0

    // fused finalize: out[node] = max(bfr(agg) (empty->0), bf16(x[node]))
    // bfr applied here once: max(bfr(v_i)) == bfr(max(v_i)) since bfr is monotone.
    {
        int nl = t >> 3, g4 = t & 7;   // 64 nodes x 8 float4-groups
        int node = nodeBase + nl;
        if (node < N_NODES) {
            const unsigned* ar = &aggL[nl * AGG_LD + g4 * 4];
            float4 o;
            if constexpr (XB) {
                ushort4 xw = ((const ushort4*)(xb + (size_t)node * IN_CH))[g4];
                o.x = fmaxf((ar[0] == ENC_NEGINF) ? 0.f : bfr(fdec(ar[0])), __uint_as_float((unsigned)xw.x << 16));
                o.y = fmaxf((ar[1] == ENC_NEGINF) ? 0.f : bfr(fdec(ar[1])), __uint_as_float((unsigned)xw.y << 16));
                o.z = fmaxf((ar[2] == ENC_NEGINF) ? 0.f : bfr(fdec(ar[2])), __uint_as_float((unsigned)xw.z << 16));
                o.w = fmaxf((ar[3] == ENC_NEGINF) ? 0.f : bfr(fdec(ar[3])), __uint_as_float((unsigned)xw.w << 16));
            } else {
                float4 xv = ((const float4*)(x + (size_t)node * IN_CH))[g4];
                o.x = fmaxf((ar[0] == ENC_NEGINF) ? 0.f : bfr(fdec(ar[0])), bfr(xv.x));
                o.y = fmaxf((ar[1] == ENC_NEGINF) ? 0.f : bfr(fdec(ar[1])), bfr(xv.y));
                o.z = fmaxf((ar[2] == ENC_NEGINF) ? 0.f : bfr(fdec(ar[2])), bfr(xv.z));
                o.w = fmaxf((ar[3] == ENC_NEGINF) ? 0.f : bfr(fdec(ar[3])), bfr(xv.w));
            }
            ((float4*)(out + (size_t)node * OUT_CH))[g4] = o;
        }
    }
}

extern "C" void kernel_launch(void* const* d_in, const int* in_sizes, int n_in,
                              void* d_out, int out_size, void* d_ws, size_t ws_size,
                              hipStream_t stream) {
    const float* x  = (const float*)d_in[0];
    const int*   ei = (const int*)d_in[1];
    const float* ea = (const float*)d_in[2];
    const float* W1 = (const float*)d_in[3];
    const float* b1 = (const float*)d_in[4];
    const float* W2 = (const float*)d_in[5];
    const float* b2 = (const float*)d_in[6];

    char* ws = (char*)d_ws;
    unsigned short* wsImg = (unsigned short*)(ws + WS_IMG);
    float* wsb1 = (float*)(ws + WS_B1);
    float* wsb2 = (float*)(ws + WS_B2);
    int* gSupCnt = (int*)(ws + WS_SUPCNT);
    int* gCnt = (int*)(ws + WS_GCNT);

    const int nE = in_sizes[1] / 2;     // 1,000,000
    float* out = (float*)d_out;

    if (ws_size >= WS_NEED_A) {
        int2* supRec = (int2*)(ws + WS_SUPREC);
        int2* rec    = (int2*)(ws + WS_REC);
        bool xbOn = ws_size >= WS_NEED_AX;
        unsigned short* xb = xbOn ? (unsigned short*)(ws + WS_XB_A) : nullptr;
        hipMemsetAsync(gSupCnt, 0, NSUP * sizeof(int), stream);
        coarse_bin<<<(nE + K1_EDGES - 1) / K1_EDGES, 512, 0, stream>>>(
            ei, nE, gSupCnt, supRec, W1, b1, W2, b2, wsImg, wsb1, wsb2);
        fine_bin<<<NSUP, 512, 0, stream>>>(gSupCnt, supRec, gCnt, rec, x, xb);
        if (xbOn)
            bucket_mlp<1><<<NB, 512, 0, stream>>>(x, xb, ea, rec, gCnt, wsImg, wsb1, wsb2, out);
        else
            bucket_mlp<0><<<NB, 512, 0, stream>>>(x, nullptr, ea, rec, gCnt, wsImg, wsb1, wsb2, out);
    } else {
        // tier B: single scattered-write binning kernel
        int2* rec = (int2*)(ws + 24576);
        bool xbOn = ws_size >= WS_NEED_BX;
        unsigned short* xb = xbOn ? (unsigned short*)(ws + WS_XB_B) : nullptr;
        hipMemsetAsync(gCnt, 0, NB_ALL * sizeof(int), stream);
        scatter_append<<<128, 512, 0, stream>>>(ei, gCnt, rec, nE, W1, b1, W2, b2,
                                                wsImg, wsb1, wsb2, x, xb);
        if (xbOn)
            bucket_mlp<1><<<NB, 512, 0, stream>>>(x, xb, ea, rec, gCnt, wsImg, wsb1, wsb2, out);
        else
            bucket_mlp<0><<<NB, 512, 0, stream>>>(x, nullptr, ea, rec, gCnt, wsImg, wsb1, wsb2, out);
    }
}

// Round 9
// 200.503 us; speedup vs baseline: 1.3781x; 1.0400x over previous
//
#include <hip/hip_runtime.h>

#define N_NODES 100000
#define IN_CH 32
#define EDGE_CH 16
#define OUT_CH 32
#define D_CAT 80
#define D_MID 56

// fine buckets: 64 nodes each
#define BKT_SHIFT 6
#define BKT_NODES 64
#define NB 1563            // ceil(100000/64), used by bucket_mlp grid
#define NB_ALL 1568        // 196 supers * 8 fines (padded)
#define CAP 1024           // fine bucket capacity (mean 640, sd 25)

// super buckets: 512 nodes = 8 fine
#define NSUP 196
#define CAP_SUP 5632       // mean 5120, sd 71 -> +7.2 sigma
#define K1_EDGES 4096
#define K2_ITERS 11        // ceil(5632/512)

#define EPB 256            // edges per chunk (512 threads: slot=t>>1, q=t&1)
#define NT_E 16            // edge tiles (16 edges each) per chunk

// fragment-major sizes (shorts)
#define W1F_SH 4096        // 2ks * 4nt * 64lane * 8   (K=64: src32 + ea16 + pad16)
#define W2F_SH 2048        // 2ks * 2nt * 64lane * 8
#define W1D_SH 2048        // 1ks * 4nt * 64lane * 8   (dst rows 32..63 of W1)
#define WIMG_SH (W1F_SH + W2F_SH + W1D_SH)   // 8192 shorts = 16384 B
#define FEATF_SH (NT_E * 2 * 64 * 8)         // 16384 shorts = 32768 B (aliased by sHF)

#define HSTRIDE 68         // f32 stride of hdstPre rows (bank spread + float4 aligned)
#define AGG_LD 33
#define ENC_NEGINF 0x007FFFFFu

typedef short short8 __attribute__((ext_vector_type(8)));
typedef float f32x4 __attribute__((ext_vector_type(4)));
typedef int i32x2 __attribute__((ext_vector_type(2)));

// ---- ws layout (bytes) ----
#define WS_IMG    0
#define WS_B1     16384
#define WS_B2     16640
#define WS_SUPCNT 16768                    // 196*4 = 784
#define WS_GCNT   17664                    // 1568*4 = 6272
#define WS_SUPREC 24576                    // 196*5632*8 = 8,830,976
#define WS_REC    8855552                  // 1568*1024*8 = 12,845,056
#define WS_XB_A   21700608                 // WS_REC + NB_ALL*CAP*8
#define XB_BYTES  6400000                  // 100000*32*2
#define WS_NEED_A ((size_t)WS_XB_A)                       // ~21.7 MB (f32 fallback)
#define WS_NEED_AX ((size_t)WS_XB_A + XB_BYTES)           // ~28.1 MB (bf16 x)
// tier B: rec directly at 24576
#define WS_XB_B   12869632                 // 24576 + NB_ALL*CAP*8
#define WS_NEED_B ((size_t)WS_XB_B)                       // ~12.9 MB
#define WS_NEED_BX ((size_t)WS_XB_B + XB_BYTES)           // ~19.3 MB

__device__ __forceinline__ unsigned fenc(float f) {
    unsigned u = __float_as_uint(f);
    return (u & 0x80000000u) ? ~u : (u | 0x80000000u);
}
__device__ __forceinline__ float fdec(unsigned u) {
    u = (u & 0x80000000u) ? (u ^ 0x80000000u) : ~u;
    return __uint_as_float(u);
}
__device__ __forceinline__ float bfr(float f) {          // RNE to bf16 grid, as f32
    unsigned u = __float_as_uint(f);
    u = (u + 0x7FFFu + ((u >> 16) & 1u)) & 0xFFFF0000u;
    return __uint_as_float(u);
}
__device__ __forceinline__ unsigned short bf16b(float f) {  // RNE to bf16 bits
    unsigned u = __float_as_uint(f);
    return (unsigned short)((u + 0x7FFFu + ((u >> 16) & 1u)) >> 16);
}
__device__ __forceinline__ short8 cvt8(float4 a, float4 b) {
    return short8{ (short)bf16b(a.x), (short)bf16b(a.y), (short)bf16b(a.z), (short)bf16b(a.w),
                   (short)bf16b(b.x), (short)bf16b(b.y), (short)bf16b(b.z), (short)bf16b(b.w) };
}

// grid-stride f32 -> bf16 conversion of x (short8 granules)
__device__ __forceinline__ void convert_x_bf16(const float* __restrict__ x,
                                               unsigned short* __restrict__ xb,
                                               int gtid, int gstride) {
    const int tot = N_NODES * IN_CH / 8;   // 400000
    for (int i = gtid; i < tot; i += gstride) {
        float4 a = ((const float4*)x)[2 * i];
        float4 b = ((const float4*)x)[2 * i + 1];
        *(short8*)&xb[i * 8] = cvt8(a, b);
    }
}

// fragment-major weight images:
//  W1F  [0,4096):      A-frags for GEMM1, K=64 = [src rows 0..31 | ea rows 64..79 | pad]
//  W2F  [4096,6144):   A-frags for GEMM2, K=64 = [W2 rows 0..55 | pad]
//  W1dF [6144,8192):   A-frags for per-node dst GEMM, K=32 = W1 rows 32..63
__device__ void build_weight_image(const float* __restrict__ W1, const float* __restrict__ b1,
                                   const float* __restrict__ W2, const float* __restrict__ b2,
                                   unsigned short* __restrict__ wsImg,
                                   float* __restrict__ wsb1, float* __restrict__ wsb2,
                                   int t, int nthr) {
    for (int s = t; s < W1F_SH; s += nthr) {
        int j = s & 7, l = (s >> 3) & 63, fi = s >> 9;     // fi 0..7
        int nt = fi & 3, ks = fi >> 2;                      // ks 0..1
        int n = nt * 16 + (l & 15), kl = ks * 32 + (l >> 4) * 8 + j;   // kl 0..63
        unsigned short v = 0;
        if (n < D_MID) {
            if (kl < 32) v = bf16b(W1[kl * D_MID + n]);                       // src
            else if (kl < 48) v = bf16b(W1[(64 + kl - 32) * D_MID + n]);      // ea
        }
        wsImg[s] = v;
    }
    for (int s = t; s < W2F_SH; s += nthr) {
        int j = s & 7, l = (s >> 3) & 63, fi = s >> 9;     // fi 0..3
        int nt = fi & 1, ks = fi >> 1;
        int n = nt * 16 + (l & 15), kl = ks * 32 + (l >> 4) * 8 + j;
        wsImg[W1F_SH + s] = (kl < D_MID) ? bf16b(W2[kl * OUT_CH + n]) : (unsigned short)0;
    }
    for (int s = t; s < W1D_SH; s += nthr) {
        int j = s & 7, l = (s >> 3) & 63, fi = s >> 9;     // fi 0..3
        int nt = fi & 3;                                    // ks = 0
        int n = nt * 16 + (l & 15), kl = (l >> 4) * 8 + j;  // kl 0..31 -> W1 row 32+kl
        wsImg[W1F_SH + W2F_SH + s] = (n < D_MID) ? bf16b(W1[(32 + kl) * D_MID + n]) : (unsigned short)0;
    }
    if (t < 64) wsb1[t] = (t < D_MID) ? bfr(b1[t]) : 0.f;
    else if (t < 96) wsb2[t - 64] = bfr(b2[t - 64]);
}

// ---------- K1: coarse bin (4096-edge tiles -> 196 super-buckets, coalesced flush) ----------
__global__ __launch_bounds__(512) void coarse_bin(
    const int* __restrict__ ei, int nE, int* __restrict__ gSupCnt, int2* __restrict__ supRec,
    const float* __restrict__ W1, const float* __restrict__ b1,
    const float* __restrict__ W2, const float* __restrict__ b2,
    unsigned short* __restrict__ wsImg, float* __restrict__ wsb1, float* __restrict__ wsb2)
{
    __shared__ int2 staged[K1_EDGES];             // 32 KB
    __shared__ int cnt[256], sc[256], cur[256], wb[256];
    const int t = threadIdx.x;
    if (blockIdx.x == 0) build_weight_image(W1, b1, W2, b2, wsImg, wsb1, wsb2, t, 512);
    if (t < 256) cnt[t] = 0;
    __syncthreads();

    const int lo = blockIdx.x * K1_EDGES;
    int rdst[8], rsrc[8];
#pragma unroll
    for (int k = 0; k < 8; ++k) {
        int e = lo + k * 512 + t;
        bool v = e < nE;
        rdst[k] = v ? __builtin_nontemporal_load(ei + nE + e) : -1;
        rsrc[k] = v ? __builtin_nontemporal_load(ei + e) : 0;
        if ((unsigned)rdst[k] >= N_NODES) rdst[k] = -1;
        if ((unsigned)rsrc[k] >= N_NODES) rsrc[k] = 0;
        if (rdst[k] >= 0) atomicAdd(&cnt[rdst[k] >> 9], 1);
    }
    __syncthreads();
    if (t < 256) sc[t] = cnt[t];
    __syncthreads();
    for (int off = 1; off < 256; off <<= 1) {
        int v = 0;
        if (t < 256 && t >= off) v = sc[t - off];
        __syncthreads();
        if (t < 256) sc[t] += v;
        __syncthreads();
    }
    if (t < NSUP) {
        int c = cnt[t];
        int excl = sc[t] - c;
        int g = c ? atomicAdd(&gSupCnt[t], c) : 0;
        wb[t] = t * CAP_SUP + g - excl;
        cur[t] = excl;
    }
    __syncthreads();
#pragma unroll
    for (int k = 0; k < 8; ++k) {
        if (rdst[k] >= 0) {
            int s = rdst[k] >> 9;
            int pos = atomicAdd(&cur[s], 1);
            int e = lo + k * 512 + t;
            staged[pos] = make_int2(rsrc[k] | (s << 24), ((rdst[k] & 511) << 20) | e);
        }
    }
    __syncthreads();
    int nv = sc[NSUP - 1];   // total valid edges staged
    for (int i = t; i < nv; i += 512) {
        int2 r = staged[i];
        int s = (unsigned)r.x >> 24;
        int addr = wb[s] + i;
        if (addr - s * CAP_SUP < CAP_SUP)
            supRec[addr] = make_int2(r.x & 0x00FFFFFF, r.y);
    }
}

// ---------- K2: fine bin (ballot-rank single pass, direct rec writes) ----------
__global__ __launch_bounds__(512) void fine_bin(
    const int* __restrict__ gSupCnt, const int2* __restrict__ supRec,
    int* __restrict__ gCnt, int2* __restrict__ rec,
    const float* __restrict__ x, unsigned short* __restrict__ xb)
{
    __shared__ int cur8[8];
    const int s = blockIdx.x, t = threadIdx.x;
    const int lane = t & 63;

    if (xb) convert_x_bf16(x, xb, s * 512 + t, NSUP * 512);

    const int cntS = min(gSupCnt[s], CAP_SUP);
    if (t < 8) cur8[t] = 0;
    __syncthreads();

    int2 r[K2_ITERS];
#pragma unroll
    for (int k = 0; k < K2_ITERS; ++k) {
        int i = k * 512 + t;
        r[k] = (i < cntS) ? supRec[(size_t)s * CAP_SUP + i] : make_int2(0, 0);
    }
#pragma unroll
    for (int k = 0; k < K2_ITERS; ++k) {
        int i = k * 512 + t;
        bool v = i < cntS;
        int f = v ? ((r[k].y >> 26) & 7) : -1;
        int rank = 0, wbase = 0;
#pragma unroll
        for (int vv = 0; vv < 8; ++vv) {
            unsigned long long m = __ballot(f == vv);
            if (lane == vv) wbase = m ? atomicAdd(&cur8[vv], (int)__popcll(m)) : 0;
            if (f == vv) rank = (int)__popcll(m & ((1ull << lane) - 1ull));
        }
        int base = __shfl(wbase, f & 7);
        if (v) {
            int pos = base + rank;
            if (pos < CAP)
                rec[(size_t)(s * 8 + f) * CAP + pos] =
                    make_int2(r[k].x, (((r[k].y >> 20) & 63) << 20) | (r[k].y & 0xFFFFF));
        }
    }
    __syncthreads();
    if (t < 8) gCnt[s * 8 + t] = min(cur8[t], CAP);
}

// ---------- tier B: single-kernel binning (scattered writes), exact same rec format ----------
__global__ __launch_bounds__(512) void scatter_append(
    const int* __restrict__ ei, int* __restrict__ gCnt, int2* __restrict__ rec, int nE,
    const float* __restrict__ W1, const float* __restrict__ b1,
    const float* __restrict__ W2, const float* __restrict__ b2,
    unsigned short* __restrict__ wsImg, float* __restrict__ wsb1, float* __restrict__ wsb2,
    const float* __restrict__ x, unsigned short* __restrict__ xb)
{
    __shared__ int lh[NB];
    __shared__ int lbase[NB];
    if (blockIdx.x == 0) build_weight_image(W1, b1, W2, b2, wsImg, wsb1, wsb2, threadIdx.x, 512);
    if (xb) convert_x_bf16(x, xb, blockIdx.x * 512 + threadIdx.x, gridDim.x * 512);
    for (int i = threadIdx.x; i < NB; i += 512) lh[i] = 0;
    __syncthreads();
    int per = (nE + gridDim.x - 1) / gridDim.x;
    int lo = blockIdx.x * per;
    int hi = min(lo + per, nE);
    for (int e = lo + threadIdx.x; e < hi; e += 512) {
        int dst = __builtin_nontemporal_load(ei + nE + e);
        if ((unsigned)dst < N_NODES) atomicAdd(&lh[dst >> BKT_SHIFT], 1);
    }
    __syncthreads();
    for (int i = threadIdx.x; i < NB; i += 512) {
        int c = lh[i];
        lbase[i] = c ? atomicAdd(&gCnt[i], c) : 0;
        lh[i] = 0;
    }
    __syncthreads();
    for (int e = lo + threadIdx.x; e < hi; e += 512) {
        int dst = __builtin_nontemporal_load(ei + nE + e);
        if ((unsigned)dst >= N_NODES) continue;
        int b = dst >> BKT_SHIFT;
        int p = lbase[b] + atomicAdd(&lh[b], 1);
        if (p >= CAP) continue;
        int src = __builtin_nontemporal_load(ei + e);
        if ((unsigned)src >= N_NODES) src = 0;
        rec[(size_t)b * CAP + p] = make_int2(src, ((dst & (BKT_NODES - 1)) << 20) | e);
    }
}

// ---------- main: per-bucket gather + MFMA MLP + LDS max + finalize ----------
// Round-9 changes vs the 76 us R8 kernel (structure otherwise identical):
//  1. Barriers B2 (GEMM1->ep1) and B3 (ep1->GEMM2) REMOVED: wave w's GEMM1 B-frags,
//     ep1 writes, and GEMM2 B-frags all touch tiles {2w,2w+1,2w+16,2w+17} -- disjoint
//     across waves, and LDS ops within a wave are processed in order, so the alias
//     hazard needs no cross-wave sync. Only B1 (storeChunk scatter -> GEMM1) and
//     B4 (GEMM2 reads -> next storeChunk) involve cross-wave tiles.
//  2. ep2 atomics carry fenc(raw acc2); bias add + LeakyReLU + bfr moved to finalize
//     (all monotone, per-column-constant -> max commutes; bits unchanged).
template<int XB>
__global__ __launch_bounds__(512, 4) void bucket_mlp(
    const float* __restrict__ x, const unsigned short* __restrict__ xb,
    const float* __restrict__ ea,
    const int2* __restrict__ rec, const int* __restrict__ gCnt,
    const unsigned short* __restrict__ wsImg,
    const float* __restrict__ wsb1, const float* __restrict__ wsb2,
    float* __restrict__ out)
{
    __shared__ unsigned short sFeatF[FEATF_SH];   // 32768 B; aliased by sHF
    __shared__ unsigned short sWgt[WIMG_SH];      // 16384 B (W1F | W2F | W1dF)
    __shared__ float sHdst[BKT_NODES * HSTRIDE];  // 17408 B (W1d·x_dst + b1, f32)
    __shared__ unsigned aggL[BKT_NODES * AGG_LD]; //  8448 B
    __shared__ float sb1f[64];
    __shared__ float sb2f[32];
    __shared__ int sdl[EPB];                      //  1024 B

    unsigned short* const sW1F = sWgt;
    unsigned short* const sW2F = sWgt + W1F_SH;
    unsigned short* const sW1D = sWgt + W1F_SH + W2F_SH;
    unsigned short* const sHF  = sFeatF;          // alias (exact same extent)

    const int t = threadIdx.x;
    const int nodeBase = blockIdx.x << BKT_SHIFT;
    const int base = blockIdx.x * CAP;
    const int cnt  = min(gCnt[blockIdx.x], CAP);

    for (int i = t; i < WIMG_SH / 8; i += 512)
        *(short8*)&sWgt[i * 8] = *(const short8*)(wsImg + i * 8);
    for (int i = t; i < BKT_NODES * AGG_LD; i += 512) aggL[i] = ENC_NEGINF;
    if (t < 64) sb1f[t] = wsb1[t];
    else if (t < 96) sb2f[t - 64] = wsb2[t - 64];

    const int wave = t >> 6;
    const int l15  = t & 15;
    const int quad = (t & 63) >> 4;
    const int lane = t & 63;
    const int slot = t >> 1, q = t & 1;
    const int sl15 = slot & 15, set = slot >> 4;   // set: edge tile 0..15

    short8 rv16[4];
    int rdl;

    auto loadRec = [&](int idx) -> i32x2 {
        return (idx < cnt) ? *(const i32x2*)(rec + base + idx) : (i32x2){0, 0};
    };
    // q=0: 4 src chunks (cols 0..31); q=1: 2 ea chunks (cols 32..47) + 2 zero pads
    auto gather = [&](i32x2 r2, bool ok) {
        rdl = ok ? ((r2.y >> 20) & 63) : -1;
        short8 z = {0, 0, 0, 0, 0, 0, 0, 0};
        if (q == 0) {
            if constexpr (XB) {
                const short8* xs8 = (const short8*)(xb + (size_t)r2.x * IN_CH);
#pragma unroll
                for (int k = 0; k < 4; ++k) rv16[k] = ok ? xs8[k] : z;
            } else {
                const float* xs = x + (size_t)r2.x * IN_CH;
#pragma unroll
                for (int k = 0; k < 4; ++k)
                    rv16[k] = ok ? cvt8(((const float4*)xs)[2 * k], ((const float4*)xs)[2 * k + 1]) : z;
            }
        } else {
            const float* ep = ea + (size_t)(r2.y & 0xFFFFF) * EDGE_CH;
#pragma unroll
            for (int k = 0; k < 2; ++k)
                rv16[k] = ok ? cvt8(((const float4*)ep)[2 * k], ((const float4*)ep)[2 * k + 1]) : z;
            rv16[2] = z; rv16[3] = z;
        }
    };
    auto storeChunk = [&]() {
        if (q == 0) sdl[slot] = rdl;
#pragma unroll
        for (int k = 0; k < 4; ++k) {
            int cj = q * 4 + k;
            int a16 = (set * 2 + (cj >> 2)) * 64 + (cj & 3) * 16 + sl15;
            *(short8*)&sFeatF[a16 * 8] = rv16[k];
        }
    };

    // prologue: rec 2 ahead, gathers 1 ahead (all global, no LDS dependency)
    i32x2 recC = loadRec(slot);
    i32x2 recN = loadRec(EPB + slot);
    gather(recC, slot < cnt);

    __syncthreads();   // weight image + biases visible

    // per-node dst pre-GEMM: hdstPre[node][c] = (W1d · x_dst)[c] + b1[c]  (c < 56, else 0)
    {
        const int ntile = wave & 3, mh = wave >> 2;
        int node = nodeBase + ntile * 16 + l15;
        short8 bfr8 = {0, 0, 0, 0, 0, 0, 0, 0};
        if (node < N_NODES) {
            if constexpr (XB) {
                bfr8 = *(const short8*)(xb + (size_t)node * IN_CH + quad * 8);
            } else {
                const float* xp = x + (size_t)node * IN_CH + quad * 8;
                bfr8 = cvt8(((const float4*)xp)[0], ((const float4*)xp)[1]);
            }
        }
        f32x4 accd[2] = {(f32x4){0.f, 0.f, 0.f, 0.f}, (f32x4){0.f, 0.f, 0.f, 0.f}};
#pragma unroll
        for (int i = 0; i < 2; ++i) {
            int nt = mh * 2 + i;
            short8 af = *(const short8*)&sW1D[(nt * 64 + lane) * 8];
            accd[i] = __builtin_amdgcn_mfma_f32_16x16x32_bf16(af, bfr8, accd[i], 0, 0, 0);
        }
#pragma unroll
        for (int i = 0; i < 2; ++i) {
            int nt = mh * 2 + i, c0 = nt * 16 + quad * 4;
            float4 vv;
#pragma unroll
            for (int j = 0; j < 4; ++j) {
                int c = c0 + j;
                ((float*)&vv)[j] = (c < D_MID) ? accd[i][j] + sb1f[c] : 0.f;
            }
            *(float4*)&sHdst[(ntile * 16 + l15) * HSTRIDE + c0] = vv;
        }
    }
    // sHdst writes become visible to other waves at the first in-loop B1.

    for (int c0e = 0; c0e < cnt; c0e += EPB) {
        storeChunk();
        __syncthreads();   // B1: cross-wave featF scatter visible before GEMM1 reads
        // issue next chunk's gathers now -> latency hidden by GEMM1+ep1+GEMM2
        gather(recN, (c0e + EPB + slot) < cnt);
        recN = loadRec(c0e + 2 * EPB + slot);

        // GEMM1: D[m=h_col][n=edge], K=64; each wave owns edge tiles {wave, wave+8}
        f32x4 acc[2][4];
#pragma unroll
        for (int ei = 0; ei < 2; ++ei)
#pragma unroll
            for (int nt = 0; nt < 4; ++nt) acc[ei][nt] = (f32x4){0.f, 0.f, 0.f, 0.f};
#pragma unroll
        for (int ks = 0; ks < 2; ++ks) {
            short8 bf0 = *(const short8*)&sFeatF[((wave * 2 + ks) * 64 + lane) * 8];
            short8 bf1 = *(const short8*)&sFeatF[(((wave + 8) * 2 + ks) * 64 + lane) * 8];
#pragma unroll
            for (int nt = 0; nt < 4; ++nt) {
                short8 af = *(const short8*)&sW1F[((ks * 4 + nt) * 64 + lane) * 8];
                acc[0][nt] = __builtin_amdgcn_mfma_f32_16x16x32_bf16(af, bf0, acc[0][nt], 0, 0, 0);
                acc[1][nt] = __builtin_amdgcn_mfma_f32_16x16x32_bf16(af, bf1, acc[1][nt], 0, 0, 0);
            }
        }
        // (B2 removed: ep1 overwrites only this wave's own GEMM1 B-frag tiles;
        //  same-wave LDS ops are processed in order.)

        // epilogue1: add hdstPre[dl] (has b1), LeakyReLU, -> fragment-major sHF
#pragma unroll
        for (int ei = 0; ei < 2; ++ei) {
            int et = wave + ei * 8;
            int dl = sdl[et * 16 + l15];
            const float* hrow = &sHdst[((dl >= 0) ? dl : 0) * HSTRIDE];
#pragma unroll
            for (int nt = 0; nt < 4; ++nt) {
                int c0 = nt * 16 + quad * 4;
                float4 hd = *(const float4*)&hrow[c0];
                int ks2 = nt >> 1;
                int quad2 = (nt * 2 + (quad >> 1)) & 3;
                int off = (quad & 1) * 4;
                ushort4 p;
#pragma unroll
                for (int j = 0; j < 4; ++j) {
                    float v = acc[ei][nt][j] + ((const float*)&hd)[j];
                    v = (v > 0.f) ? v : 0.01f * v;
                    ((unsigned short*)&p)[j] = (c0 + j < D_MID) ? bf16b(v) : (unsigned short)0;
                }
                *(ushort4*)&sHF[((et * 2 + ks2) * 64 + quad2 * 16 + l15) * 8 + off] = p;
            }
        }
        // (B3 removed: GEMM2 reads only this wave's own ep1-written tiles.)

        // GEMM2: D[m=out_col][n=edge], K=64
        f32x4 acc2[2][2];
#pragma unroll
        for (int ei = 0; ei < 2; ++ei)
#pragma unroll
            for (int nt = 0; nt < 2; ++nt) acc2[ei][nt] = (f32x4){0.f, 0.f, 0.f, 0.f};
#pragma unroll
        for (int ks = 0; ks < 2; ++ks) {
            short8 bf0 = *(const short8*)&sHF[((wave * 2 + ks) * 64 + lane) * 8];
            short8 bf1 = *(const short8*)&sHF[(((wave + 8) * 2 + ks) * 64 + lane) * 8];
#pragma unroll
            for (int nt = 0; nt < 2; ++nt) {
                short8 af = *(const short8*)&sW2F[((ks * 2 + nt) * 64 + lane) * 8];
                acc2[0][nt] = __builtin_amdgcn_mfma_f32_16x16x32_bf16(af, bf0, acc2[0][nt], 0, 0, 0);
                acc2[1][nt] = __builtin_amdgcn_mfma_f32_16x16x32_bf16(af, bf1, acc2[1][nt], 0, 0, 0);
            }
        }

        // epilogue2: LDS scatter-max on RAW acc2 order-encoding (bias+leaky+bfr deferred)
#pragma unroll
        for (int ei = 0; ei < 2; ++ei) {
            int et = wave + ei * 8;
            int dl = sdl[et * 16 + l15];
            if (dl >= 0) {
                unsigned* arow = &aggL[dl * AGG_LD];
#pragma unroll
                for (int nt = 0; nt < 2; ++nt) {
                    int c0 = nt * 16 + quad * 4;
#pragma unroll
                    for (int j = 0; j < 4; ++j)
                        atomicMax(arow + c0 + j, fenc(acc2[ei][nt][j]));
                }
            }
        }
        __syncthreads();   // B4: sHF reads + atomics done before next storeChunk
    }
    __syncthreads();       // covers cnt==0

    // fused finalize: agg holds max(raw acc2); apply +b2, LeakyReLU, bfr ONCE here
    // (all monotone per-column transforms -> commutes with max; bits unchanged).
    {
        int nl = t >> 3, g4 = t & 7;   // 64 nodes x 8 float4-groups
        int node = nodeBase + nl;
        if (node < N_NODES) {
            const unsigned* ar = &aggL[nl * AGG_LD + g4 * 4];
            float av[4];
#pragma unroll
            for (int j = 0; j < 4; ++j) {
                if (ar[j] == ENC_NEGINF) { av[j] = 0.f; }
                else {
                    float v = fdec(ar[j]) + sb2f[g4 * 4 + j];
                    v = (v > 0.f) ? v : 0.01f * v;
                    av[j] = bfr(v);
                }
            }
            float4 o;
            if constexpr (XB) {
                ushort4 xw = ((const ushort4*)(xb + (size_t)node * IN_CH))[g4];
                o.x = fmaxf(av[0], __uint_as_float((unsigned)xw.x << 16));
                o.y = fmaxf(av[1], __uint_as_float((unsigned)xw.y << 16));
                o.z = fmaxf(av[2], __uint_as_float((unsigned)xw.z << 16));
                o.w = fmaxf(av[3], __uint_as_float((unsigned)xw.w << 16));
            } else {
                float4 xv = ((const float4*)(x + (size_t)node * IN_CH))[g4];
                o.x = fmaxf(av[0], bfr(xv.x));
                o.y = fmaxf(av[1], bfr(xv.y));
                o.z = fmaxf(av[2], bfr(xv.z));
                o.w = fmaxf(av[3], bfr(xv.w));
            }
            ((float4*)(out + (size_t)node * OUT_CH))[g4] = o;
        }
    }
}

extern "C" void kernel_launch(void* const* d_in, const int* in_sizes, int n_in,
                              void* d_out, int out_size, void* d_ws, size_t ws_size,
                              hipStream_t stream) {
    const float* x  = (const float*)d_in[0];
    const int*   ei = (const int*)d_in[1];
    const float* ea = (const float*)d_in[2];
    const float* W1 = (const float*)d_in[3];
    const float* b1 = (const float*)d_in[4];
    const float* W2 = (const float*)d_in[5];
    const float* b2 = (const float*)d_in[6];

    char* ws = (char*)d_ws;
    unsigned short* wsImg = (unsigned short*)(ws + WS_IMG);
    float* wsb1 = (float*)(ws + WS_B1);
    float* wsb2 = (float*)(ws + WS_B2);
    int* gSupCnt = (int*)(ws + WS_SUPCNT);
    int* gCnt = (int*)(ws + WS_GCNT);

    const int nE = in_sizes[1] / 2;     // 1,000,000
    float* out = (float*)d_out;

    if (ws_size >= WS_NEED_A) {
        int2* supRec = (int2*)(ws + WS_SUPREC);
        int2* rec    = (int2*)(ws + WS_REC);
        bool xbOn = ws_size >= WS_NEED_AX;
        unsigned short* xb = xbOn ? (unsigned short*)(ws + WS_XB_A) : nullptr;
        hipMemsetAsync(gSupCnt, 0, NSUP * sizeof(int), stream);
        coarse_bin<<<(nE + K1_EDGES - 1) / K1_EDGES, 512, 0, stream>>>(
            ei, nE, gSupCnt, supRec, W1, b1, W2, b2, wsImg, wsb1, wsb2);
        fine_bin<<<NSUP, 512, 0, stream>>>(gSupCnt, supRec, gCnt, rec, x, xb);
        if (xbOn)
            bucket_mlp<1><<<NB, 512, 0, stream>>>(x, xb, ea, rec, gCnt, wsImg, wsb1, wsb2, out);
        else
            bucket_mlp<0><<<NB, 512, 0, stream>>>(x, nullptr, ea, rec, gCnt, wsImg, wsb1, wsb2, out);
    } else {
        // tier B: single scattered-write binning kernel
        int2* rec = (int2*)(ws + 24576);
        bool xbOn = ws_size >= WS_NEED_BX;
        unsigned short* xb = xbOn ? (unsigned short*)(ws + WS_XB_B) : nullptr;
        hipMemsetAsync(gCnt, 0, NB_ALL * sizeof(int), stream);
        scatter_append<<<128, 512, 0, stream>>>(ei, gCnt, rec, nE, W1, b1, W2, b2,
                                                wsImg, wsb1, wsb2, x, xb);
        if (xbOn)
            bucket_mlp<1><<<NB, 512, 0, stream>>>(x, xb, ea, rec, gCnt, wsImg, wsb1, wsb2, out);
        else
            bucket_mlp<0><<<NB, 512, 0, stream>>>(x, nullptr, ea, rec, gCnt, wsImg, wsb1, wsb2, out);
    }
}